// Round 8
// baseline (262.068 us; speedup 1.0000x reference)
//
#include <hip/hip_runtime.h>
#include <hip/hip_bf16.h>

using bf16 = __hip_bfloat16;
typedef __attribute__((ext_vector_type(8))) short short8;   // 8 bf16 (4 VGPRs)
typedef __attribute__((ext_vector_type(4))) float floatx4;  // MFMA C/D frag

#define NPn 4096
#define NCn 1024
#define Dn  512
#define Bn  4

__device__ __forceinline__ float b2f(short s) {
    union { unsigned u; float f; } cv;
    cv.u = ((unsigned)(unsigned short)s) << 16;
    return cv.f;
}

// ---------------------------------------------------------------------------
// async global->LDS, 16B per lane. LDS dest = (wave-uniform base) + lane*16B.
// ---------------------------------------------------------------------------
__device__ __forceinline__ void async_copy16(const bf16* g, bf16* l) {
    __builtin_amdgcn_global_load_lds(
        (const __attribute__((address_space(1))) unsigned int*)g,
        (__attribute__((address_space(3))) unsigned int*)l,
        16, 0, 0);
}

#define SBAR()  __builtin_amdgcn_s_barrier()
#define SCHED0() __builtin_amdgcn_sched_barrier(0)

// LDS chunk swizzle (Round 8): f(row) = (row&3) ^ ((row>>2)&3).
// Involution both-sides (stage pre-swizzles global source chunk, ds_read
// XORs the same f). Old f=row&3 left rows r,r+4 on identical banks (4-way
// conflict, 1.57M/dispatch measured); new f spreads mod-4 row groups across
// all 4 chunks -> residual 2-way (free, m136).
#define FROW(r) (((r) & 3) ^ (((r) >> 2) & 3))

// ---------------------------------------------------------------------------
// 256x256-tile 8-phase GEMM (T2+T3+T4+T5 port of the m201 template).
// C[M x N] = scale * A[M x K] * Bt[N x K]^T, row-major bf16 in, OutT out.
// 512 threads = 8 waves as 2(M) x 4(N); per-wave output 128x64 = acc[8][4].
// K consumed in BK=64 tiles, each as two k-32 halves (ks=0,1).
// LDS [buf][ks][256][32] bf16, 128 KB total, double buffered.
//
// STATS: fused row/col stat partials in the epilogue (replaces stats_both).
//   rp[(b*4  + bn/256)*M + bm + r] = (sum,sq,max) over this block's 256 cols
//   cp[(b*16 + bm/256)*N + bn + c] = (sum,sq,max) over this block's 256 rows
//
// bf16 epilogue (Round 8): per-wave LDS-staged transpose of the 128x64
// output -> 16B short8 stores (was 32x scalar 2B stores -> 32B segments).
// Scratch = Asl reuse, wave-private 16x68 f32 region, no extra barriers
// beyond one __syncthreads before first reuse (DS ops are per-wave in-order).
//
// Per-thread vmcnt ledger (stageA/stageB = 2 ops each, retire in order):
//  prologue stages 8 ops, vmcnt(4) -> klo landed, khi(4) in flight.
//  P0 +2 (A-klo t+1) =6; P1 +2 (B-klo t+1) =8, vmcnt(4) retires t's khi.
//  P2 +2 (A-khi t+1) =6; P3 +2 (B-khi t+1) =8, vmcnt(4) retires t+1's klo.
// vmcnt never 0 in the main loop (T4). Last tile peeled: vmcnt(0) at P1.
// ---------------------------------------------------------------------------
template <typename OutT, bool RS, bool STATS>
__global__ __launch_bounds__(512) void gemm256(
    const bf16* __restrict__ A, const bf16* __restrict__ B, OutT* __restrict__ C,
    int M, int N, int K, long strideA, long strideB, long strideC,
    float scale, int nbat, const float* __restrict__ rsc,
    float4* __restrict__ rp, float4* __restrict__ cp)
{
    const int z = blockIdx.z;
    const int b = z % nbat;
    A += (long)b * strideA;
    B += (long)b * strideB;
    C += (long)z * strideC;

    // XCD-aware bijective swizzle of the (bx,by) plane (m204).
    const int nwg = gridDim.x * gridDim.y;
    const int orig = blockIdx.y * gridDim.x + blockIdx.x;
    const int q = nwg >> 3, r = nwg & 7;
    const int xcd = orig & 7, pos = orig >> 3;
    const int nid = (xcd < r ? xcd * (q + 1) : r * (q + 1) + (xcd - r) * q) + pos;
    const int bm = (nid / gridDim.x) * 256;
    const int bn = (nid % gridDim.x) * 256;

    const int tid = threadIdx.x;
    const int lane = tid & 63;
    const int wave = tid >> 6;                 // 0..7
    const int wm2 = (wave >> 2) * 128;         // wave's M offset (0/128)
    const int wn2 = (wave & 3) * 64;           // wave's N offset (0/64/128/192)
    const int mrow = lane & 15;
    const int g = lane >> 4;                   // k-chunk group 0..3

    __shared__ bf16 Asl[2][2][256][32];        // [buf][ks][row][col] 64 KB
    __shared__ bf16 Bsl[2][2][256][32];        // 64 KB

    floatx4 acc[8][4];
#pragma unroll
    for (int i = 0; i < 8; i++)
#pragma unroll
        for (int j = 0; j < 4; j++) acc[i][j] = (floatx4)(0.0f);

    const int s0 = wave * 64 + lane;
    const int sr = s0 >> 2, sc = s0 & 3;
    auto stageA = [&](int kb, int ks, int buf) {
        const int cg = (sc ^ FROW(sr)) * 8;    // FROW(sr+128)==FROW(sr)
        const bf16* src0 = A + (long)(bm + sr) * K + kb + ks * 32 + cg;
        const bf16* src1 = A + (long)(bm + sr + 128) * K + kb + ks * 32 + cg;
        bf16* base = &Asl[buf][ks][0][0];
        async_copy16(src0, base + wave * 512);
        async_copy16(src1, base + 4096 + wave * 512);
    };
    auto stageB = [&](int kb, int ks, int buf) {
        const int cg = (sc ^ FROW(sr)) * 8;
        const bf16* src0 = B + (long)(bn + sr) * K + kb + ks * 32 + cg;
        const bf16* src1 = B + (long)(bn + sr + 128) * K + kb + ks * 32 + cg;
        bf16* base = &Bsl[buf][ks][0][0];
        async_copy16(src0, base + wave * 512);
        async_copy16(src1, base + 4096 + wave * 512);
    };
    auto ldA = [&](int buf, int ks, int mi) -> short8 {
        const int row = wm2 + mi * 16 + mrow;
        const int cc = (g ^ FROW(row)) * 8;
        return *(const short8*)(&Asl[buf][ks][row][cc]);
    };
    auto ldB = [&](int buf, int ks, int ni) -> short8 {
        const int row = wn2 + ni * 16 + mrow;
        const int cc = (g ^ FROW(row)) * 8;
        return *(const short8*)(&Bsl[buf][ks][row][cc]);
    };

#define MFMA_GRP(MS)                                                          \
    do {                                                                      \
        _Pragma("unroll") for (int i = 0; i < 4; i++)                         \
            _Pragma("unroll") for (int j = 0; j < 4; j++)                     \
                acc[(MS) + i][j] = __builtin_amdgcn_mfma_f32_16x16x32_bf16(   \
                    a[i], bb[j], acc[(MS) + i][j], 0, 0, 0);                  \
    } while (0)

    const int nt = K / 64;
    stageA(0, 0, 0); stageB(0, 0, 0);
    stageA(0, 1, 0); stageB(0, 1, 0);
    asm volatile("s_waitcnt vmcnt(4)" ::: "memory");
    SBAR(); SCHED0();

    int cur = 0;
    for (int t = 0; t < nt - 1; ++t) {
        const int nxt = cur ^ 1;
        const int kb1 = (t + 1) * 64;
        short8 a[4], bb[4];
        // ---- P0 ----
#pragma unroll
        for (int i = 0; i < 4; i++) a[i] = ldA(cur, 0, i);
#pragma unroll
        for (int j = 0; j < 4; j++) bb[j] = ldB(cur, 0, j);
        stageA(kb1, 0, nxt);
        SBAR();
        asm volatile("s_waitcnt lgkmcnt(0)" ::: "memory");
        SCHED0();
        __builtin_amdgcn_s_setprio(1);
        MFMA_GRP(0);
        __builtin_amdgcn_s_setprio(0);
        SCHED0(); SBAR(); SCHED0();
        // ---- P1 ----
#pragma unroll
        for (int i = 0; i < 4; i++) a[i] = ldA(cur, 0, 4 + i);
        stageB(kb1, 0, nxt);
        asm volatile("s_waitcnt vmcnt(4)" ::: "memory");   // t's khi landed
        SBAR();
        asm volatile("s_waitcnt lgkmcnt(0)" ::: "memory");
        SCHED0();
        __builtin_amdgcn_s_setprio(1);
        MFMA_GRP(4);
        __builtin_amdgcn_s_setprio(0);
        SCHED0(); SBAR(); SCHED0();
        // ---- P2 ----
#pragma unroll
        for (int i = 0; i < 4; i++) a[i] = ldA(cur, 1, i);
#pragma unroll
        for (int j = 0; j < 4; j++) bb[j] = ldB(cur, 1, j);
        stageA(kb1, 1, nxt);
        SBAR();
        asm volatile("s_waitcnt lgkmcnt(0)" ::: "memory");
        SCHED0();
        __builtin_amdgcn_s_setprio(1);
        MFMA_GRP(0);
        __builtin_amdgcn_s_setprio(0);
        SCHED0(); SBAR(); SCHED0();
        // ---- P3 ----
#pragma unroll
        for (int i = 0; i < 4; i++) a[i] = ldA(cur, 1, 4 + i);
        stageB(kb1, 1, nxt);
        asm volatile("s_waitcnt vmcnt(4)" ::: "memory");   // t+1's klo landed
        SBAR();
        asm volatile("s_waitcnt lgkmcnt(0)" ::: "memory");
        SCHED0();
        __builtin_amdgcn_s_setprio(1);
        MFMA_GRP(4);
        __builtin_amdgcn_s_setprio(0);
        SCHED0(); SBAR(); SCHED0();
        cur = nxt;
    }
    // ---- last tile (no staging) ----
    {
        short8 a[4], bb[4];
#pragma unroll
        for (int i = 0; i < 4; i++) a[i] = ldA(cur, 0, i);
#pragma unroll
        for (int j = 0; j < 4; j++) bb[j] = ldB(cur, 0, j);
        SBAR();
        asm volatile("s_waitcnt lgkmcnt(0)" ::: "memory");
        SCHED0();
        MFMA_GRP(0);
        SCHED0(); SBAR(); SCHED0();
#pragma unroll
        for (int i = 0; i < 4; i++) a[i] = ldA(cur, 0, 4 + i);
        asm volatile("s_waitcnt vmcnt(0)" ::: "memory");   // its khi landed
        SBAR();
        asm volatile("s_waitcnt lgkmcnt(0)" ::: "memory");
        SCHED0();
        MFMA_GRP(4);
        SCHED0(); SBAR(); SCHED0();
#pragma unroll
        for (int i = 0; i < 4; i++) a[i] = ldA(cur, 1, i);
#pragma unroll
        for (int j = 0; j < 4; j++) bb[j] = ldB(cur, 1, j);
        asm volatile("s_waitcnt lgkmcnt(0)" ::: "memory");
        SCHED0();
        MFMA_GRP(0);
#pragma unroll
        for (int i = 0; i < 4; i++) a[i] = ldA(cur, 1, 4 + i);
        asm volatile("s_waitcnt lgkmcnt(0)" ::: "memory");
        SCHED0();
        MFMA_GRP(4);
    }
#undef MFMA_GRP

    const int crow = (lane >> 4) * 4;
    const int ccol = lane & 15;

    if constexpr (STATS) {
        // All waves' ds_reads are complete (per-wave lgkm0 before last MFMA);
        // barrier so Asl/Bsl can be reused as reduction scratch.
        __syncthreads();
        float* rst = (float*)&Asl[0][0][0][0];   // [nw(4)][plane(3)][256 rows]
        float* cst = (float*)&Bsl[0][0][0][0];   // [mw(2)][plane(3)][256 cols]
        const int nw = wave & 3, mw = wave >> 2;
        const int rg = lane >> 4, cl = lane & 15;

        float cs[4], cq[4], cm[4];
#pragma unroll
        for (int j = 0; j < 4; j++) { cs[j] = 0.f; cq[j] = 0.f; cm[j] = -3.4e38f; }

#pragma unroll
        for (int i = 0; i < 8; i++) {
            float rs[4], rq[4], rm[4];
#pragma unroll
            for (int r2 = 0; r2 < 4; r2++) { rs[r2] = 0.f; rq[r2] = 0.f; rm[r2] = -3.4e38f; }
#pragma unroll
            for (int j = 0; j < 4; j++)
#pragma unroll
                for (int r2 = 0; r2 < 4; r2++) {
                    float v = acc[i][j][r2] * scale;
                    rs[r2] += v; rq[r2] += v * v; rm[r2] = fmaxf(rm[r2], v);
                    cs[j] += v; cq[j] += v * v; cm[j] = fmaxf(cm[j], v);
                }
            // reduce across the 16 col-lanes (row fixed per (rg,r2))
#pragma unroll
            for (int m = 1; m < 16; m <<= 1)
#pragma unroll
                for (int r2 = 0; r2 < 4; r2++) {
                    rs[r2] += __shfl_xor(rs[r2], m);
                    rq[r2] += __shfl_xor(rq[r2], m);
                    rm[r2] = fmaxf(rm[r2], __shfl_xor(rm[r2], m));
                }
            if (cl == 0) {
#pragma unroll
                for (int r2 = 0; r2 < 4; r2++) {
                    int row = wm2 + i * 16 + rg * 4 + r2;
                    rst[nw * 768 + row] = rs[r2];
                    rst[nw * 768 + 256 + row] = rq[r2];
                    rst[nw * 768 + 512 + row] = rm[r2];
                }
            }
        }
        // reduce across the 4 row-groups (col fixed per (j,cl))
#pragma unroll
        for (int m = 16; m < 64; m <<= 1)
#pragma unroll
            for (int j = 0; j < 4; j++) {
                cs[j] += __shfl_xor(cs[j], m);
                cq[j] += __shfl_xor(cq[j], m);
                cm[j] = fmaxf(cm[j], __shfl_xor(cm[j], m));
            }
        if (rg == 0) {
#pragma unroll
            for (int j = 0; j < 4; j++) {
                int col = wn2 + j * 16 + cl;
                cst[mw * 768 + col] = cs[j];
                cst[mw * 768 + 256 + col] = cq[j];
                cst[mw * 768 + 512 + col] = cm[j];
            }
        }
        __syncthreads();
        if (tid < 256) {
            float s = 0.f, qq = 0.f, m = -3.4e38f;
#pragma unroll
            for (int w = 0; w < 4; w++) {
                s += rst[w * 768 + tid];
                qq += rst[w * 768 + 256 + tid];
                m = fmaxf(m, rst[w * 768 + 512 + tid]);
            }
            rp[((long)(b * 4 + (bn >> 8))) * M + bm + tid] = make_float4(s, qq, m, 0.f);
            float s2 = cst[tid] + cst[768 + tid];
            float q2 = cst[256 + tid] + cst[768 + 256 + tid];
            float m2 = fmaxf(cst[512 + tid], cst[768 + 512 + tid]);
            cp[((long)(b * 16 + (bm >> 8))) * N + bn + tid] = make_float4(s2, q2, m2, 0.f);
        }
    }

    // epilogue: C store
    float inv_[8][4];
#pragma unroll
    for (int i = 0; i < 8; i++)
#pragma unroll
        for (int r2 = 0; r2 < 4; r2++) {
            if constexpr (RS)
                inv_[i][r2] = 1.0f / rsc[(long)b * M + bm + wm2 + i * 16 + crow + r2];
            else
                inv_[i][r2] = 1.0f;
        }
    if constexpr (__is_same(OutT, float)) {
        // fp32: scalar dword stores (16 lanes x 4B = 64B segments, OK)
#pragma unroll
        for (int i = 0; i < 8; i++) {
#pragma unroll
            for (int j = 0; j < 4; j++) {
#pragma unroll
                for (int r2 = 0; r2 < 4; r2++) {
                    long rr = bm + wm2 + i * 16 + crow + r2;
                    long cc = bn + wn2 + j * 16 + ccol;
                    C[rr * (long)N + cc] = acc[i][j][r2] * scale * inv_[i][r2];
                }
            }
        }
    } else {
        // bf16: per-wave LDS-staged vectorized stores (16B short8).
        __syncthreads();   // K-loop (and STATS scratch) LDS use complete
        float* scr = (float*)&Asl[0][0][0][0] + wave * 1088;   // 16 x 68 f32
        const int row2 = lane >> 2, cq2 = lane & 3;
#pragma unroll
        for (int i = 0; i < 8; i++) {
#pragma unroll
            for (int j = 0; j < 4; j++)
#pragma unroll
                for (int r2 = 0; r2 < 4; r2++)
                    scr[(crow + r2) * 68 + j * 16 + ccol] =
                        acc[i][j][r2] * scale * inv_[i][r2];
            // wave-private region: DS in-order per wave, compiler inserts
            // lgkmcnt waits for the RAW dependency. No barrier needed.
            bf16 tmp[16] __attribute__((aligned(16)));
#pragma unroll
            for (int qq = 0; qq < 4; qq++) {
                float4 v4 = *(const float4*)&scr[row2 * 68 + cq2 * 16 + qq * 4];
                tmp[qq * 4 + 0] = __float2bfloat16(v4.x);
                tmp[qq * 4 + 1] = __float2bfloat16(v4.y);
                tmp[qq * 4 + 2] = __float2bfloat16(v4.z);
                tmp[qq * 4 + 3] = __float2bfloat16(v4.w);
            }
            OutT* dst = C + (long)(bm + wm2 + i * 16 + row2) * N + bn + wn2 + cq2 * 16;
            *(short8*)dst = *(const short8*)tmp;
            *(short8*)(dst + 8) = *(const short8*)(tmp + 8);
        }
    }
}

// ---------------------------------------------------------------------------
// 256x128-tile GEMM, dense-2-phase (Round 6, verified). Used for the two
// N=512 GEMMs where a 256-wide tile would underfill the chip.
// 512 threads = 8 waves as 4(M) x 2(N); per-wave output 64x64 = acc[4][4].
// LDS: A[2][2][256][32] 64 KB + B[2][2][128][32] 32 KB = 96 KB, dbuf.
// Split-K: z = s*nbat + b; partial slot s at C + z*strideC.
// vmcnt(3) steady-state, never 0 in main loop (ledger in Round-6 notes).
// Round 8: FROW swizzle; bf16 out path LDS-staged vectorized (as gemm256).
// ---------------------------------------------------------------------------
template <typename OutT, bool RS>
__global__ __launch_bounds__(512) void gemm256n128(
    const bf16* __restrict__ A, const bf16* __restrict__ B, OutT* __restrict__ C,
    int M, int N, int K, long strideA, long strideB, long strideC,
    float scale, int nbat, int splits, const float* __restrict__ rsc)
{
    const int z = blockIdx.z;
    const int b = z % nbat;
    const int s = z / nbat;
    const int klen = K / splits;
    const int k0 = s * klen;

    A += (long)b * strideA;
    B += (long)b * strideB;
    C += (long)z * strideC;

    const int nwg = gridDim.x * gridDim.y;
    const int orig = blockIdx.y * gridDim.x + blockIdx.x;
    const int q = nwg >> 3, r = nwg & 7;
    const int xcd = orig & 7, pos = orig >> 3;
    const int nid = (xcd < r ? xcd * (q + 1) : r * (q + 1) + (xcd - r) * q) + pos;
    const int bm = (nid / gridDim.x) * 256;
    const int bn = (nid % gridDim.x) * 128;

    const int tid = threadIdx.x;
    const int lane = tid & 63;
    const int wave = tid >> 6;                 // 0..7
    const int wm2 = (wave >> 1) * 64;          // wave's M offset
    const int wn2 = (wave & 1) * 64;           // wave's N offset
    const int mrow = lane & 15;
    const int g = lane >> 4;

    __shared__ bf16 Asl[2][2][256][32];        // 64 KB
    __shared__ bf16 Bsl[2][2][128][32];        // 32 KB

    floatx4 acc[4][4];
#pragma unroll
    for (int i = 0; i < 4; i++)
#pragma unroll
        for (int j = 0; j < 4; j++) acc[i][j] = (floatx4)(0.0f);

    const int s0 = wave * 64 + lane;
    const int sr = s0 >> 2, sc = s0 & 3;
    auto stageA = [&](int kb, int ks, int buf) {
        const int cg = (sc ^ FROW(sr)) * 8;
        const bf16* src0 = A + (long)(bm + sr) * K + kb + ks * 32 + cg;
        const bf16* src1 = A + (long)(bm + sr + 128) * K + kb + ks * 32 + cg;
        bf16* base = &Asl[buf][ks][0][0];
        async_copy16(src0, base + wave * 512);
        async_copy16(src1, base + 4096 + wave * 512);
    };
    auto stageB = [&](int kb, int ks, int buf) {
        const int cg = (sc ^ FROW(sr)) * 8;
        const bf16* src0 = B + (long)(bn + sr) * K + kb + ks * 32 + cg;
        bf16* base = &Bsl[buf][ks][0][0];
        async_copy16(src0, base + wave * 512);
    };
    auto ldA = [&](int buf, int ks, int mi) -> short8 {
        const int row = wm2 + mi * 16 + mrow;
        const int cc = (g ^ FROW(row)) * 8;
        return *(const short8*)(&Asl[buf][ks][row][cc]);
    };
    auto ldB = [&](int buf, int ks, int ni) -> short8 {
        const int row = wn2 + ni * 16 + mrow;
        const int cc = (g ^ FROW(row)) * 8;
        return *(const short8*)(&Bsl[buf][ks][row][cc]);
    };

#define MFMA_GRP16()                                                          \
    do {                                                                      \
        _Pragma("unroll") for (int i = 0; i < 4; i++)                         \
            _Pragma("unroll") for (int j = 0; j < 4; j++)                     \
                acc[i][j] = __builtin_amdgcn_mfma_f32_16x16x32_bf16(          \
                    a[i], bb[j], acc[i][j], 0, 0, 0);                         \
    } while (0)

    const int nt = klen / 64;
    stageA(k0, 0, 0); stageB(k0, 0, 0);
    stageA(k0, 1, 0); stageB(k0, 1, 0);
    asm volatile("s_waitcnt vmcnt(3)" ::: "memory");
    SBAR(); SCHED0();

    int cur = 0;
    for (int t = 0; t < nt - 1; ++t) {
        const int nxt = cur ^ 1;
        const int kb1 = k0 + (t + 1) * 64;
        short8 a[4], bb[4];
        // ---- P0: k-half 0 ----
#pragma unroll
        for (int i = 0; i < 4; i++) a[i] = ldA(cur, 0, i);
#pragma unroll
        for (int j = 0; j < 4; j++) bb[j] = ldB(cur, 0, j);
        stageA(kb1, 0, nxt);
        stageB(kb1, 0, nxt);
        asm volatile("s_waitcnt vmcnt(3)" ::: "memory");   // t's khi landed
        SBAR();
        asm volatile("s_waitcnt lgkmcnt(0)" ::: "memory");
        SCHED0();
        __builtin_amdgcn_s_setprio(1);
        MFMA_GRP16();
        __builtin_amdgcn_s_setprio(0);
        SCHED0(); SBAR(); SCHED0();
        // ---- P1: k-half 1 ----
#pragma unroll
        for (int i = 0; i < 4; i++) a[i] = ldA(cur, 1, i);
#pragma unroll
        for (int j = 0; j < 4; j++) bb[j] = ldB(cur, 1, j);
        stageA(kb1, 1, nxt);
        stageB(kb1, 1, nxt);
        asm volatile("s_waitcnt vmcnt(3)" ::: "memory");   // t+1's klo landed
        SBAR();
        asm volatile("s_waitcnt lgkmcnt(0)" ::: "memory");
        SCHED0();
        __builtin_amdgcn_s_setprio(1);
        MFMA_GRP16();
        __builtin_amdgcn_s_setprio(0);
        SCHED0(); SBAR(); SCHED0();
        cur = nxt;
    }
    // ---- last tile (no staging) ----
    {
        short8 a[4], bb[4];
#pragma unroll
        for (int i = 0; i < 4; i++) a[i] = ldA(cur, 0, i);
#pragma unroll
        for (int j = 0; j < 4; j++) bb[j] = ldB(cur, 0, j);
        asm volatile("s_waitcnt vmcnt(0)" ::: "memory");
        SBAR();
        asm volatile("s_waitcnt lgkmcnt(0)" ::: "memory");
        SCHED0();
        __builtin_amdgcn_s_setprio(1);
        MFMA_GRP16();
        __builtin_amdgcn_s_setprio(0);
        SCHED0(); SBAR(); SCHED0();
#pragma unroll
        for (int i = 0; i < 4; i++) a[i] = ldA(cur, 1, i);
#pragma unroll
        for (int j = 0; j < 4; j++) bb[j] = ldB(cur, 1, j);
        asm volatile("s_waitcnt lgkmcnt(0)" ::: "memory");
        SCHED0();
        MFMA_GRP16();
    }
#undef MFMA_GRP16

    const int crow = (lane >> 4) * 4;
    const int ccol = lane & 15;
    float inv_[4][4];
#pragma unroll
    for (int i = 0; i < 4; i++)
#pragma unroll
        for (int r2 = 0; r2 < 4; r2++) {
            if constexpr (RS)
                inv_[i][r2] = 1.0f / rsc[(long)b * M + bm + wm2 + i * 16 + crow + r2];
            else
                inv_[i][r2] = 1.0f;
        }
    if constexpr (__is_same(OutT, float)) {
#pragma unroll
        for (int i = 0; i < 4; i++) {
#pragma unroll
            for (int j = 0; j < 4; j++) {
#pragma unroll
                for (int r2 = 0; r2 < 4; r2++) {
                    long rr = bm + wm2 + i * 16 + crow + r2;
                    long cc = bn + wn2 + j * 16 + ccol;
                    C[rr * (long)N + cc] = acc[i][j][r2] * scale * inv_[i][r2];
                }
            }
        }
    } else {
        __syncthreads();   // K-loop LDS use complete before scratch reuse
        float* scr = (float*)&Asl[0][0][0][0] + wave * 1088;   // 16 x 68 f32
        const int row2 = lane >> 2, cq2 = lane & 3;
#pragma unroll
        for (int i = 0; i < 4; i++) {
#pragma unroll
            for (int j = 0; j < 4; j++)
#pragma unroll
                for (int r2 = 0; r2 < 4; r2++)
                    scr[(crow + r2) * 68 + j * 16 + ccol] =
                        acc[i][j][r2] * scale * inv_[i][r2];
            bf16 tmp[16] __attribute__((aligned(16)));
#pragma unroll
            for (int qq = 0; qq < 4; qq++) {
                float4 v4 = *(const float4*)&scr[row2 * 68 + cq2 * 16 + qq * 4];
                tmp[qq * 4 + 0] = __float2bfloat16(v4.x);
                tmp[qq * 4 + 1] = __float2bfloat16(v4.y);
                tmp[qq * 4 + 2] = __float2bfloat16(v4.z);
                tmp[qq * 4 + 3] = __float2bfloat16(v4.w);
            }
            OutT* dst = C + (long)(bm + wm2 + i * 16 + row2) * N + bn + wn2 + cq2 * 16;
            *(short8*)dst = *(const short8*)tmp;
            *(short8*)(dst + 8) = *(const short8*)(tmp + 8);
        }
    }
}

// ---------------------------------------------------------------------------
// Finalize stats; thr = mean + std(ddof=1)/8. Also zeros d1/d2.
// Row partials from gemm256<STATS>: 4 slots; col partials 16 slots.
// ---------------------------------------------------------------------------
__global__ __launch_bounds__(256) void stats_final(
    const float4* __restrict__ rp, const float4* __restrict__ cp,
    float2* __restrict__ row_tm, float2* __restrict__ col_tm,
    float* __restrict__ d1, float* __restrict__ d2)
{
    int idx = blockIdx.x * 256 + threadIdx.x;
    if (idx < Bn * NPn) {
        int b = idx >> 12, p = idx & (NPn - 1);
        float s = 0.f, q = 0.f, m = -3.4e38f;
#pragma unroll
        for (int i = 0; i < 4; i++) {
            float4 v = rp[((long)(b * 4 + i)) * NPn + p];
            s += v.x; q += v.y; m = fmaxf(m, v.z);
        }
        float mean = s * (1.0f / NCn);
        float var = fmaxf((q - (float)NCn * mean * mean) * (1.0f / (NCn - 1)), 0.0f);
        row_tm[idx] = make_float2(mean + sqrtf(var) * 0.125f, m);
        d1[idx] = 0.f;
    } else {
        int cidx = idx - Bn * NPn;
        int b = cidx >> 10, c = cidx & (NCn - 1);
        float s = 0.f, q = 0.f, m = -3.4e38f;
#pragma unroll
        for (int i = 0; i < 16; i++) {
            float4 v = cp[((long)(b * 16 + i)) * NCn + c];
            s += v.x; q += v.y; m = fmaxf(m, v.z);
        }
        float mean = s * (1.0f / NPn);
        float var = fmaxf((q - (float)NPn * mean * mean) * (1.0f / (NPn - 1)), 0.0f);
        col_tm[cidx] = make_float2(mean + sqrtf(var) * 0.125f, m);
        d2[cidx] = 0.f;
    }
}

// ---------------------------------------------------------------------------
// Merged masked softmax v2: one read of S produces A1u (row-major) and A2u
// (transposed); d1/d2 via atomics. 2 x 128-row halves -> T[64][133] = 34 KB
// -> 4 blocks/CU.
// ---------------------------------------------------------------------------
__global__ __launch_bounds__(256) void softmax_merged(
    const bf16* __restrict__ S, const float2* __restrict__ row_tm,
    const float2* __restrict__ col_tm, float* __restrict__ d1,
    float* __restrict__ d2, bf16* __restrict__ A1u, bf16* __restrict__ A2u)
{
    const int b = blockIdx.z, c0 = blockIdx.x * 64, p0 = blockIdx.y * 256;
    const int tid = threadIdx.x;
    const int rt = tid >> 3;          // 0..31 row within pass
    const int ct = (tid & 7) * 8;     // col offset, 8 cols per thread

    __shared__ float T[64][133];      // transposed e2 staging (1 half-tile)
    __shared__ float dw2[4][64];      // per-wave col-denom partials

    float2 ctm[8];
#pragma unroll
    for (int t = 0; t < 8; t++) ctm[t] = col_tm[b * NCn + c0 + ct + t];

    float d2acc[8];
#pragma unroll
    for (int t = 0; t < 8; t++) d2acc[t] = 0.f;

    for (int half = 0; half < 2; ++half) {
#pragma unroll
        for (int pass = 0; pass < 4; pass++) {
            const int p = p0 + half * 128 + pass * 32 + rt;
            const float2 rtm = row_tm[b * NPn + p];
            const long sidx = ((long)(b * NPn + p)) * NCn + c0 + ct;
            short8 sv = *(const short8*)(S + sidx);
            bf16 o1[8] __attribute__((aligned(16)));
            float e1s = 0.f;
#pragma unroll
            for (int t = 0; t < 8; t++) {
                float x = b2f(sv[t]);
                float e1 = (x >= rtm.x) ? __expf(x - rtm.y) : 0.0f;
                o1[t] = __float2bfloat16(e1);
                e1s += e1;
                float e2 = (x >= ctm[t].x) ? __expf(x - ctm[t].y) : 0.0f;
                d2acc[t] += e2;
                T[ct + t][pass * 32 + rt] = e2;
            }
            *(short8*)(A1u + sidx) = *(const short8*)o1;
            e1s += __shfl_xor(e1s, 1);
            e1s += __shfl_xor(e1s, 2);
            e1s += __shfl_xor(e1s, 4);
            if ((tid & 7) == 0) atomicAdd(&d1[b * NPn + p], e1s);
        }
        __syncthreads();
        // flush this half's A2u rows (transposed) from LDS
        {
            const int c = tid >> 2, pb = (tid & 3) * 32;
            bf16* dst = A2u + ((long)(b * NCn + c0 + c)) * NPn + p0 + half * 128 + pb;
#pragma unroll
            for (int u = 0; u < 4; u++) {
                bf16 tmp[8] __attribute__((aligned(16)));
#pragma unroll
                for (int w = 0; w < 8; w++)
                    tmp[w] = __float2bfloat16(T[c][pb + u * 8 + w]);
                *(short8*)(dst + u * 8) = *(const short8*)tmp;
            }
        }
        __syncthreads();   // T reusable for next half
    }

    // col denominators: reduce d2acc across rt within wave, then LDS
#pragma unroll
    for (int m = 8; m < 64; m <<= 1)
#pragma unroll
        for (int t = 0; t < 8; t++) d2acc[t] += __shfl_xor(d2acc[t], m);
    const int lane = tid & 63, wave = tid >> 6;
    if (lane < 8)
#pragma unroll
        for (int t = 0; t < 8; t++) dw2[wave][lane * 8 + t] = d2acc[t];
    __syncthreads();
    if (tid < 64)
        atomicAdd(&d2[b * NCn + c0 + tid],
                  dw2[0][tid] + dw2[1][tid] + dw2[2][tid] + dw2[3][tid]);
}

// ---------------------------------------------------------------------------
// Sum 4 split-K fp32 partials, scale row (b*NC+c) by 1/d2 -> bf16
// ---------------------------------------------------------------------------
__global__ __launch_bounds__(256) void reduce_scale_bf16(
    const float* __restrict__ Pp, const float* __restrict__ d2,
    bf16* __restrict__ out, long n4, long stride)
{
    long i = (long)blockIdx.x * 256 + threadIdx.x;
    if (i < n4) {
        float4 a = ((const float4*)Pp)[i];
#pragma unroll
        for (int s = 1; s < 4; s++) {
            float4 v = ((const float4*)(Pp + (long)s * stride))[i];
            a.x += v.x; a.y += v.y; a.z += v.z; a.w += v.w;
        }
        float inv = 1.0f / d2[i / (Dn / 4)];
        out[i * 4 + 0] = __float2bfloat16(a.x * inv);
        out[i * 4 + 1] = __float2bfloat16(a.y * inv);
        out[i * 4 + 2] = __float2bfloat16(a.z * inv);
        out[i * 4 + 3] = __float2bfloat16(a.w * inv);
    }
}

// ---------------------------------------------------------------------------
// fp32 [R x C] -> bf16 row-major copy AND bf16 [C x R] transpose, batched z.
// ---------------------------------------------------------------------------
__global__ __launch_bounds__(256) void cvt_both(
    const float* __restrict__ in, bf16* __restrict__ out_rm,
    bf16* __restrict__ out_t, int R, int C)
{
    __shared__ float tile[32][33];
    const long boff = (long)blockIdx.z * (long)R * C;
    in += boff; out_rm += boff; out_t += boff;
    const int c0 = blockIdx.x * 32, r0 = blockIdx.y * 32;
    const int tx = threadIdx.x, ty = threadIdx.y;
#pragma unroll
    for (int i = ty; i < 32; i += 8) {
        float x = in[(long)(r0 + i) * C + c0 + tx];
        tile[i][tx] = x;
        out_rm[(long)(r0 + i) * C + c0 + tx] = __float2bfloat16(x);
    }
    __syncthreads();
#pragma unroll
    for (int i = ty; i < 32; i += 8)
        out_t[(long)(c0 + i) * R + r0 + tx] = __float2bfloat16(tile[tx][i]);
}

// ---------------------------------------------------------------------------
extern "C" void kernel_launch(void* const* d_in, const int* in_sizes, int n_in,
                              void* d_out, int out_size, void* d_ws, size_t ws_size,
                              hipStream_t stream)
{
    const float* Xp = (const float*)d_in[0];  // [4,4096,512]
    const float* Xc = (const float*)d_in[1];  // [4,1024,512]
    float* out = (float*)d_out;               // [4,4096,1024]

    constexpr int B = Bn, NP = NPn, NC = NCn, D = Dn;
    constexpr float SCALE = 0.044194173824159216f;  // 1/sqrt(512)

    // workspace layout (bytes), ~164 MB
    char* ws = (char*)d_ws;
    bf16*   Qp     = (bf16*)(ws);                   // 16.78 MB [B,NP,D]
    bf16*   Kc     = (bf16*)(ws + 16777216);        //  4.19 MB [B,NC,D]
    bf16*   KcT    = (bf16*)(ws + 20971520);        //  4.19 MB [B,D,NC]
    bf16*   XpT    = (bf16*)(ws + 25165824);        // 16.78 MB [B,D,NP]
    bf16*   S      = (bf16*)(ws + 41943040);        // 33.55 MB [B,NP,NC]; later Hp overlays
    bf16*   A1u    = (bf16*)(ws + 75497472);        // 33.55 MB [B,NP,NC]
    bf16*   A2u    = (bf16*)(ws + 109051904);       // 33.55 MB [B,NC,NP]; rp/cp overlay pre-softmax
    bf16*   H1u    = (bf16*)(ws + 142606336);       // 16.78 MB [B,NP,D]
    bf16*   H2     = (bf16*)(ws + 159383552);       //  4.19 MB [B,NC,D]
    float2* row_tm = (float2*)(ws + 163577856);     // 128 KB  [B*NP]
    float2* col_tm = (float2*)(ws + 163708928);     //  32 KB  [B*NC]
    float*  d1     = (float*)(ws + 163741696);      //  64 KB  [B*NP]
    float*  d2     = (float*)(ws + 163807232);      //  16 KB  [B*NC]
    float4* rp     = (float4*)A2u;                  //  1.05 MB [B*4,NP]
    float4* cp     = (float4*)(ws + 109051904 + 4194304);  // 1.05 MB [B*16,NC]
    float*  Hp     = (float*)S;                     // split-K partials [4][B,NC,D] fp32 (S dead)

    // 1-2: convert + transpose inputs (one read of fp32 each)
    cvt_both<<<dim3(D / 32, NP / 32, B), dim3(32, 8), 0, stream>>>(Xp, Qp, XpT, NP, D);
    cvt_both<<<dim3(D / 32, NC / 32, B), dim3(32, 8), 0, stream>>>(Xc, Kc, KcT, NC, D);

    // 3: S = Qp*Kc^T*scale (bf16) -- 256x256 8-phase, fused row/col stats
    gemm256<bf16, false, true><<<dim3(NC / 256, NP / 256, B), dim3(512), 0, stream>>>(
        Qp, Kc, S, NP, NC, D, (long)NP * D, (long)NC * D, (long)NP * NC,
        SCALE, B, nullptr, rp, cp);
    // 4: finalize thr/max (rows: 4 partials, cols: 16); zero denoms
    stats_final<<<dim3((B * NP + B * NC) / 256), dim3(256), 0, stream>>>(
        rp, cp, row_tm, col_tm, d1, d2);
    // 5: merged softmax -> A1u + A2u (transposed), denoms via atomics
    softmax_merged<<<dim3(NC / 64, NP / 256, B), dim3(256), 0, stream>>>(
        S, row_tm, col_tm, d1, d2, A1u, A2u);
    // 6: H1u = A1u * Kc  [B,NP,D] bf16 -- 256x128 dense-2-phase
    gemm256n128<bf16, false><<<dim3(D / 128, NP / 256, B), dim3(512), 0, stream>>>(
        A1u, KcT, H1u, NP, D, NC, (long)NP * NC, (long)D * NC, (long)NP * D,
        1.0f, B, 1, nullptr);
    // 7: Hp = A2u * Xp partials [4][B,NC,D] fp32, 4-way split-K
    gemm256n128<float, false><<<dim3(D / 128, NC / 256, 4 * B), dim3(512), 0, stream>>>(
        A2u, XpT, Hp, NC, D, NP, (long)NC * NP, (long)D * NP, (long)NC * D,
        1.0f, B, 4, nullptr);
    // 8: H2 = sum(Hp) / d2 -> bf16
    {
        long n = (long)B * NC * D;
        reduce_scale_bf16<<<dim3((n / 4 + 255) / 256), dim3(256), 0, stream>>>(
            Hp, d2, H2, n / 4, n);
    }
    // 9: out = diag(1/d1) * H1u * H2^T   [B,NP,NC] fp32 -- 256x256 8-phase
    gemm256<float, true, false><<<dim3(NC / 256, NP / 256, B), dim3(512), 0, stream>>>(
        H1u, H2, out, NP, NC, D, (long)NP * D, (long)NC * D, (long)NP * NC,
        1.0f, B, d1, nullptr, nullptr);
}

// Round 9
// 252.787 us; speedup vs baseline: 1.0367x; 1.0367x over previous
//
#include <hip/hip_runtime.h>
#include <hip/hip_bf16.h>

using bf16 = __hip_bfloat16;
typedef __attribute__((ext_vector_type(8))) short short8;   // 8 bf16 (4 VGPRs)
typedef __attribute__((ext_vector_type(4))) float floatx4;  // MFMA C/D frag

#define NPn 4096
#define NCn 1024
#define Dn  512
#define Bn  4

__device__ __forceinline__ float b2f(short s) {
    union { unsigned u; float f; } cv;
    cv.u = ((unsigned)(unsigned short)s) << 16;
    return cv.f;
}

// ---------------------------------------------------------------------------
// async global->LDS, 16B per lane. LDS dest = (wave-uniform base) + lane*16B.
// ---------------------------------------------------------------------------
__device__ __forceinline__ void async_copy16(const bf16* g, bf16* l) {
    __builtin_amdgcn_global_load_lds(
        (const __attribute__((address_space(1))) unsigned int*)g,
        (__attribute__((address_space(3))) unsigned int*)l,
        16, 0, 0);
}

#define SBAR()  __builtin_amdgcn_s_barrier()
#define SCHED0() __builtin_amdgcn_sched_barrier(0)

// ---------------------------------------------------------------------------
// 256x256-tile 8-phase GEMM (T2+T3+T4+T5 port of the m201 template).
// C[M x N] = scale * A[M x K] * Bt[N x K]^T, row-major bf16 in, OutT out.
// 512 threads = 8 waves as 2(M) x 4(N); per-wave output 128x64 = acc[8][4].
// K consumed in BK=64 tiles, each as two k-32 halves (ks=0,1).
// LDS [buf][ks][256][32] bf16, 128 KB total, double buffered.
// Round-7 state (verified 257.5 us). Round-8's FROW swizzle + LDS-staged
// epilogue REGRESSED (bank-conflict 1.57M->2.98M, dur 40.5->67 us) and are
// reverted: chunk-XOR swizzle = row&3, scalar C stores.
//
// STATS: fused row/col stat partials in the epilogue (replaces stats_both).
//   rp[(b*4  + bn/256)*M + bm + r] = (sum,sq,max) over this block's 256 cols
//   cp[(b*16 + bm/256)*N + bn + c] = (sum,sq,max) over this block's 256 rows
//
// Per-thread vmcnt ledger (stageA/stageB = 2 ops each, retire in order):
//  prologue stages 8 ops, vmcnt(4) -> klo landed, khi(4) in flight.
//  P0 +2 (A-klo t+1) =6; P1 +2 (B-klo t+1) =8, vmcnt(4) retires t's khi.
//  P2 +2 (A-khi t+1) =6; P3 +2 (B-khi t+1) =8, vmcnt(4) retires t+1's klo.
// vmcnt never 0 in the main loop (T4). Last tile peeled: vmcnt(0) at P1.
// ---------------------------------------------------------------------------
template <typename OutT, bool RS, bool STATS>
__global__ __launch_bounds__(512) void gemm256(
    const bf16* __restrict__ A, const bf16* __restrict__ B, OutT* __restrict__ C,
    int M, int N, int K, long strideA, long strideB, long strideC,
    float scale, int nbat, const float* __restrict__ rsc,
    float4* __restrict__ rp, float4* __restrict__ cp)
{
    const int z = blockIdx.z;
    const int b = z % nbat;
    A += (long)b * strideA;
    B += (long)b * strideB;
    C += (long)z * strideC;

    // XCD-aware bijective swizzle of the (bx,by) plane (m204).
    const int nwg = gridDim.x * gridDim.y;
    const int orig = blockIdx.y * gridDim.x + blockIdx.x;
    const int q = nwg >> 3, r = nwg & 7;
    const int xcd = orig & 7, pos = orig >> 3;
    const int nid = (xcd < r ? xcd * (q + 1) : r * (q + 1) + (xcd - r) * q) + pos;
    const int bm = (nid / gridDim.x) * 256;
    const int bn = (nid % gridDim.x) * 256;

    const int tid = threadIdx.x;
    const int lane = tid & 63;
    const int wave = tid >> 6;                 // 0..7
    const int wm2 = (wave >> 2) * 128;         // wave's M offset (0/128)
    const int wn2 = (wave & 3) * 64;           // wave's N offset (0/64/128/192)
    const int mrow = lane & 15;
    const int g = lane >> 4;                   // k-chunk group 0..3

    __shared__ bf16 Asl[2][2][256][32];        // [buf][ks][row][col] 64 KB
    __shared__ bf16 Bsl[2][2][256][32];        // 64 KB

    floatx4 acc[8][4];
#pragma unroll
    for (int i = 0; i < 8; i++)
#pragma unroll
        for (int j = 0; j < 4; j++) acc[i][j] = (floatx4)(0.0f);

    const int s0 = wave * 64 + lane;
    const int sr = s0 >> 2, sc = s0 & 3;
    auto stageA = [&](int kb, int ks, int buf) {
        const int cg = (sc ^ (sr & 3)) * 8;
        const bf16* src0 = A + (long)(bm + sr) * K + kb + ks * 32 + cg;
        const bf16* src1 = A + (long)(bm + sr + 128) * K + kb + ks * 32 + cg;
        bf16* base = &Asl[buf][ks][0][0];
        async_copy16(src0, base + wave * 512);
        async_copy16(src1, base + 4096 + wave * 512);
    };
    auto stageB = [&](int kb, int ks, int buf) {
        const int cg = (sc ^ (sr & 3)) * 8;
        const bf16* src0 = B + (long)(bn + sr) * K + kb + ks * 32 + cg;
        const bf16* src1 = B + (long)(bn + sr + 128) * K + kb + ks * 32 + cg;
        bf16* base = &Bsl[buf][ks][0][0];
        async_copy16(src0, base + wave * 512);
        async_copy16(src1, base + 4096 + wave * 512);
    };
    auto ldA = [&](int buf, int ks, int mi) -> short8 {
        const int row = wm2 + mi * 16 + mrow;
        const int cc = (g ^ (row & 3)) * 8;
        return *(const short8*)(&Asl[buf][ks][row][cc]);
    };
    auto ldB = [&](int buf, int ks, int ni) -> short8 {
        const int row = wn2 + ni * 16 + mrow;
        const int cc = (g ^ (row & 3)) * 8;
        return *(const short8*)(&Bsl[buf][ks][row][cc]);
    };

#define MFMA_GRP(MS)                                                          \
    do {                                                                      \
        _Pragma("unroll") for (int i = 0; i < 4; i++)                         \
            _Pragma("unroll") for (int j = 0; j < 4; j++)                     \
                acc[(MS) + i][j] = __builtin_amdgcn_mfma_f32_16x16x32_bf16(   \
                    a[i], bb[j], acc[(MS) + i][j], 0, 0, 0);                  \
    } while (0)

    const int nt = K / 64;
    stageA(0, 0, 0); stageB(0, 0, 0);
    stageA(0, 1, 0); stageB(0, 1, 0);
    asm volatile("s_waitcnt vmcnt(4)" ::: "memory");
    SBAR(); SCHED0();

    int cur = 0;
    for (int t = 0; t < nt - 1; ++t) {
        const int nxt = cur ^ 1;
        const int kb1 = (t + 1) * 64;
        short8 a[4], bb[4];
        // ---- P0 ----
#pragma unroll
        for (int i = 0; i < 4; i++) a[i] = ldA(cur, 0, i);
#pragma unroll
        for (int j = 0; j < 4; j++) bb[j] = ldB(cur, 0, j);
        stageA(kb1, 0, nxt);
        SBAR();
        asm volatile("s_waitcnt lgkmcnt(0)" ::: "memory");
        SCHED0();
        __builtin_amdgcn_s_setprio(1);
        MFMA_GRP(0);
        __builtin_amdgcn_s_setprio(0);
        SCHED0(); SBAR(); SCHED0();
        // ---- P1 ----
#pragma unroll
        for (int i = 0; i < 4; i++) a[i] = ldA(cur, 0, 4 + i);
        stageB(kb1, 0, nxt);
        asm volatile("s_waitcnt vmcnt(4)" ::: "memory");   // t's khi landed
        SBAR();
        asm volatile("s_waitcnt lgkmcnt(0)" ::: "memory");
        SCHED0();
        __builtin_amdgcn_s_setprio(1);
        MFMA_GRP(4);
        __builtin_amdgcn_s_setprio(0);
        SCHED0(); SBAR(); SCHED0();
        // ---- P2 ----
#pragma unroll
        for (int i = 0; i < 4; i++) a[i] = ldA(cur, 1, i);
#pragma unroll
        for (int j = 0; j < 4; j++) bb[j] = ldB(cur, 1, j);
        stageA(kb1, 1, nxt);
        SBAR();
        asm volatile("s_waitcnt lgkmcnt(0)" ::: "memory");
        SCHED0();
        __builtin_amdgcn_s_setprio(1);
        MFMA_GRP(0);
        __builtin_amdgcn_s_setprio(0);
        SCHED0(); SBAR(); SCHED0();
        // ---- P3 ----
#pragma unroll
        for (int i = 0; i < 4; i++) a[i] = ldA(cur, 1, 4 + i);
        stageB(kb1, 1, nxt);
        asm volatile("s_waitcnt vmcnt(4)" ::: "memory");   // t+1's klo landed
        SBAR();
        asm volatile("s_waitcnt lgkmcnt(0)" ::: "memory");
        SCHED0();
        __builtin_amdgcn_s_setprio(1);
        MFMA_GRP(4);
        __builtin_amdgcn_s_setprio(0);
        SCHED0(); SBAR(); SCHED0();
        cur = nxt;
    }
    // ---- last tile (no staging) ----
    {
        short8 a[4], bb[4];
#pragma unroll
        for (int i = 0; i < 4; i++) a[i] = ldA(cur, 0, i);
#pragma unroll
        for (int j = 0; j < 4; j++) bb[j] = ldB(cur, 0, j);
        SBAR();
        asm volatile("s_waitcnt lgkmcnt(0)" ::: "memory");
        SCHED0();
        MFMA_GRP(0);
        SCHED0(); SBAR(); SCHED0();
#pragma unroll
        for (int i = 0; i < 4; i++) a[i] = ldA(cur, 0, 4 + i);
        asm volatile("s_waitcnt vmcnt(0)" ::: "memory");   // its khi landed
        SBAR();
        asm volatile("s_waitcnt lgkmcnt(0)" ::: "memory");
        SCHED0();
        MFMA_GRP(4);
        SCHED0(); SBAR(); SCHED0();
#pragma unroll
        for (int i = 0; i < 4; i++) a[i] = ldA(cur, 1, i);
#pragma unroll
        for (int j = 0; j < 4; j++) bb[j] = ldB(cur, 1, j);
        asm volatile("s_waitcnt lgkmcnt(0)" ::: "memory");
        SCHED0();
        MFMA_GRP(0);
#pragma unroll
        for (int i = 0; i < 4; i++) a[i] = ldA(cur, 1, 4 + i);
        asm volatile("s_waitcnt lgkmcnt(0)" ::: "memory");
        SCHED0();
        MFMA_GRP(4);
    }
#undef MFMA_GRP

    const int crow = (lane >> 4) * 4;
    const int ccol = lane & 15;

    if constexpr (STATS) {
        // All waves' ds_reads are complete (per-wave lgkm0 before last MFMA);
        // barrier so Asl/Bsl can be reused as reduction scratch.
        __syncthreads();
        float* rst = (float*)&Asl[0][0][0][0];   // [nw(4)][plane(3)][256 rows]
        float* cst = (float*)&Bsl[0][0][0][0];   // [mw(2)][plane(3)][256 cols]
        const int nw = wave & 3, mw = wave >> 2;
        const int rg = lane >> 4, cl = lane & 15;

        float cs[4], cq[4], cm[4];
#pragma unroll
        for (int j = 0; j < 4; j++) { cs[j] = 0.f; cq[j] = 0.f; cm[j] = -3.4e38f; }

#pragma unroll
        for (int i = 0; i < 8; i++) {
            float rs[4], rq[4], rm[4];
#pragma unroll
            for (int r2 = 0; r2 < 4; r2++) { rs[r2] = 0.f; rq[r2] = 0.f; rm[r2] = -3.4e38f; }
#pragma unroll
            for (int j = 0; j < 4; j++)
#pragma unroll
                for (int r2 = 0; r2 < 4; r2++) {
                    float v = acc[i][j][r2] * scale;
                    rs[r2] += v; rq[r2] += v * v; rm[r2] = fmaxf(rm[r2], v);
                    cs[j] += v; cq[j] += v * v; cm[j] = fmaxf(cm[j], v);
                }
            // reduce across the 16 col-lanes (row fixed per (rg,r2))
#pragma unroll
            for (int m = 1; m < 16; m <<= 1)
#pragma unroll
                for (int r2 = 0; r2 < 4; r2++) {
                    rs[r2] += __shfl_xor(rs[r2], m);
                    rq[r2] += __shfl_xor(rq[r2], m);
                    rm[r2] = fmaxf(rm[r2], __shfl_xor(rm[r2], m));
                }
            if (cl == 0) {
#pragma unroll
                for (int r2 = 0; r2 < 4; r2++) {
                    int row = wm2 + i * 16 + rg * 4 + r2;
                    rst[nw * 768 + row] = rs[r2];
                    rst[nw * 768 + 256 + row] = rq[r2];
                    rst[nw * 768 + 512 + row] = rm[r2];
                }
            }
        }
        // reduce across the 4 row-groups (col fixed per (j,cl))
#pragma unroll
        for (int m = 16; m < 64; m <<= 1)
#pragma unroll
            for (int j = 0; j < 4; j++) {
                cs[j] += __shfl_xor(cs[j], m);
                cq[j] += __shfl_xor(cq[j], m);
                cm[j] = fmaxf(cm[j], __shfl_xor(cm[j], m));
            }
        if (rg == 0) {
#pragma unroll
            for (int j = 0; j < 4; j++) {
                int col = wn2 + j * 16 + cl;
                cst[mw * 768 + col] = cs[j];
                cst[mw * 768 + 256 + col] = cq[j];
                cst[mw * 768 + 512 + col] = cm[j];
            }
        }
        __syncthreads();
        if (tid < 256) {
            float s = 0.f, qq = 0.f, m = -3.4e38f;
#pragma unroll
            for (int w = 0; w < 4; w++) {
                s += rst[w * 768 + tid];
                qq += rst[w * 768 + 256 + tid];
                m = fmaxf(m, rst[w * 768 + 512 + tid]);
            }
            rp[((long)(b * 4 + (bn >> 8))) * M + bm + tid] = make_float4(s, qq, m, 0.f);
            float s2 = cst[tid] + cst[768 + tid];
            float q2 = cst[256 + tid] + cst[768 + 256 + tid];
            float m2 = fmaxf(cst[512 + tid], cst[768 + 512 + tid]);
            cp[((long)(b * 16 + (bm >> 8))) * N + bn + tid] = make_float4(s2, q2, m2, 0.f);
        }
    }

    // epilogue: C store (scalar — stores are fire-and-forget; Round-8's
    // LDS-staged variant regressed via lgkm RAW stalls)
    float inv_[8][4];
#pragma unroll
    for (int i = 0; i < 8; i++)
#pragma unroll
        for (int r2 = 0; r2 < 4; r2++) {
            if constexpr (RS)
                inv_[i][r2] = 1.0f / rsc[(long)b * M + bm + wm2 + i * 16 + crow + r2];
            else
                inv_[i][r2] = 1.0f;
        }
#pragma unroll
    for (int i = 0; i < 8; i++) {
#pragma unroll
        for (int j = 0; j < 4; j++) {
#pragma unroll
            for (int r2 = 0; r2 < 4; r2++) {
                long rr = bm + wm2 + i * 16 + crow + r2;
                long cc = bn + wn2 + j * 16 + ccol;
                float v = acc[i][j][r2] * scale * inv_[i][r2];
                if constexpr (__is_same(OutT, float))
                    C[rr * (long)N + cc] = v;
                else
                    C[rr * (long)N + cc] = __float2bfloat16(v);
            }
        }
    }
}

// ---------------------------------------------------------------------------
// 256x128-tile GEMM, dense-2-phase (Round 6, verified). Used for the two
// N=512 GEMMs where a 256-wide tile would underfill the chip.
// 512 threads = 8 waves as 4(M) x 2(N); per-wave output 64x64 = acc[4][4].
// LDS: A[2][2][256][32] 64 KB + B[2][2][128][32] 32 KB = 96 KB, dbuf.
// Split-K: z = s*nbat + b; partial slot s at C + z*strideC.
// vmcnt(3) steady-state, never 0 in main loop.
// ---------------------------------------------------------------------------
template <typename OutT, bool RS>
__global__ __launch_bounds__(512) void gemm256n128(
    const bf16* __restrict__ A, const bf16* __restrict__ B, OutT* __restrict__ C,
    int M, int N, int K, long strideA, long strideB, long strideC,
    float scale, int nbat, int splits, const float* __restrict__ rsc)
{
    const int z = blockIdx.z;
    const int b = z % nbat;
    const int s = z / nbat;
    const int klen = K / splits;
    const int k0 = s * klen;

    A += (long)b * strideA;
    B += (long)b * strideB;
    C += (long)z * strideC;

    const int nwg = gridDim.x * gridDim.y;
    const int orig = blockIdx.y * gridDim.x + blockIdx.x;
    const int q = nwg >> 3, r = nwg & 7;
    const int xcd = orig & 7, pos = orig >> 3;
    const int nid = (xcd < r ? xcd * (q + 1) : r * (q + 1) + (xcd - r) * q) + pos;
    const int bm = (nid / gridDim.x) * 256;
    const int bn = (nid % gridDim.x) * 128;

    const int tid = threadIdx.x;
    const int lane = tid & 63;
    const int wave = tid >> 6;                 // 0..7
    const int wm2 = (wave >> 1) * 64;          // wave's M offset
    const int wn2 = (wave & 1) * 64;           // wave's N offset
    const int mrow = lane & 15;
    const int g = lane >> 4;

    __shared__ bf16 Asl[2][2][256][32];        // 64 KB
    __shared__ bf16 Bsl[2][2][128][32];        // 32 KB

    floatx4 acc[4][4];
#pragma unroll
    for (int i = 0; i < 4; i++)
#pragma unroll
        for (int j = 0; j < 4; j++) acc[i][j] = (floatx4)(0.0f);

    const int s0 = wave * 64 + lane;
    const int sr = s0 >> 2, sc = s0 & 3;
    auto stageA = [&](int kb, int ks, int buf) {
        const int cg = (sc ^ (sr & 3)) * 8;
        const bf16* src0 = A + (long)(bm + sr) * K + kb + ks * 32 + cg;
        const bf16* src1 = A + (long)(bm + sr + 128) * K + kb + ks * 32 + cg;
        bf16* base = &Asl[buf][ks][0][0];
        async_copy16(src0, base + wave * 512);
        async_copy16(src1, base + 4096 + wave * 512);
    };
    auto stageB = [&](int kb, int ks, int buf) {
        const int cg = (sc ^ (sr & 3)) * 8;
        const bf16* src0 = B + (long)(bn + sr) * K + kb + ks * 32 + cg;
        bf16* base = &Bsl[buf][ks][0][0];
        async_copy16(src0, base + wave * 512);
    };
    auto ldA = [&](int buf, int ks, int mi) -> short8 {
        const int row = wm2 + mi * 16 + mrow;
        const int cc = (g ^ (row & 3)) * 8;
        return *(const short8*)(&Asl[buf][ks][row][cc]);
    };
    auto ldB = [&](int buf, int ks, int ni) -> short8 {
        const int row = wn2 + ni * 16 + mrow;
        const int cc = (g ^ (row & 3)) * 8;
        return *(const short8*)(&Bsl[buf][ks][row][cc]);
    };

#define MFMA_GRP16()                                                          \
    do {                                                                      \
        _Pragma("unroll") for (int i = 0; i < 4; i++)                         \
            _Pragma("unroll") for (int j = 0; j < 4; j++)                     \
                acc[i][j] = __builtin_amdgcn_mfma_f32_16x16x32_bf16(          \
                    a[i], bb[j], acc[i][j], 0, 0, 0);                         \
    } while (0)

    const int nt = klen / 64;
    stageA(k0, 0, 0); stageB(k0, 0, 0);
    stageA(k0, 1, 0); stageB(k0, 1, 0);
    asm volatile("s_waitcnt vmcnt(3)" ::: "memory");
    SBAR(); SCHED0();

    int cur = 0;
    for (int t = 0; t < nt - 1; ++t) {
        const int nxt = cur ^ 1;
        const int kb1 = k0 + (t + 1) * 64;
        short8 a[4], bb[4];
        // ---- P0: k-half 0 ----
#pragma unroll
        for (int i = 0; i < 4; i++) a[i] = ldA(cur, 0, i);
#pragma unroll
        for (int j = 0; j < 4; j++) bb[j] = ldB(cur, 0, j);
        stageA(kb1, 0, nxt);
        stageB(kb1, 0, nxt);
        asm volatile("s_waitcnt vmcnt(3)" ::: "memory");   // t's khi landed
        SBAR();
        asm volatile("s_waitcnt lgkmcnt(0)" ::: "memory");
        SCHED0();
        __builtin_amdgcn_s_setprio(1);
        MFMA_GRP16();
        __builtin_amdgcn_s_setprio(0);
        SCHED0(); SBAR(); SCHED0();
        // ---- P1: k-half 1 ----
#pragma unroll
        for (int i = 0; i < 4; i++) a[i] = ldA(cur, 1, i);
#pragma unroll
        for (int j = 0; j < 4; j++) bb[j] = ldB(cur, 1, j);
        stageA(kb1, 1, nxt);
        stageB(kb1, 1, nxt);
        asm volatile("s_waitcnt vmcnt(3)" ::: "memory");   // t+1's klo landed
        SBAR();
        asm volatile("s_waitcnt lgkmcnt(0)" ::: "memory");
        SCHED0();
        __builtin_amdgcn_s_setprio(1);
        MFMA_GRP16();
        __builtin_amdgcn_s_setprio(0);
        SCHED0(); SBAR(); SCHED0();
        cur = nxt;
    }
    // ---- last tile (no staging) ----
    {
        short8 a[4], bb[4];
#pragma unroll
        for (int i = 0; i < 4; i++) a[i] = ldA(cur, 0, i);
#pragma unroll
        for (int j = 0; j < 4; j++) bb[j] = ldB(cur, 0, j);
        asm volatile("s_waitcnt vmcnt(0)" ::: "memory");
        SBAR();
        asm volatile("s_waitcnt lgkmcnt(0)" ::: "memory");
        SCHED0();
        __builtin_amdgcn_s_setprio(1);
        MFMA_GRP16();
        __builtin_amdgcn_s_setprio(0);
        SCHED0(); SBAR(); SCHED0();
#pragma unroll
        for (int i = 0; i < 4; i++) a[i] = ldA(cur, 1, i);
#pragma unroll
        for (int j = 0; j < 4; j++) bb[j] = ldB(cur, 1, j);
        asm volatile("s_waitcnt lgkmcnt(0)" ::: "memory");
        SCHED0();
        MFMA_GRP16();
    }
#undef MFMA_GRP16

    const int crow = (lane >> 4) * 4;
    const int ccol = lane & 15;
    float inv_[4][4];
#pragma unroll
    for (int i = 0; i < 4; i++)
#pragma unroll
        for (int r2 = 0; r2 < 4; r2++) {
            if constexpr (RS)
                inv_[i][r2] = 1.0f / rsc[(long)b * M + bm + wm2 + i * 16 + crow + r2];
            else
                inv_[i][r2] = 1.0f;
        }
#pragma unroll
    for (int i = 0; i < 4; i++) {
#pragma unroll
        for (int j = 0; j < 4; j++) {
#pragma unroll
            for (int r2 = 0; r2 < 4; r2++) {
                long rr = bm + wm2 + i * 16 + crow + r2;
                long cc = bn + wn2 + j * 16 + ccol;
                float v = acc[i][j][r2] * scale * inv_[i][r2];
                if constexpr (__is_same(OutT, float))
                    C[rr * (long)N + cc] = v;
                else
                    C[rr * (long)N + cc] = __float2bfloat16(v);
            }
        }
    }
}

// ---------------------------------------------------------------------------
// Finalize stats; thr = mean + std(ddof=1)/8. Also zeros d1/d2.
// Row partials from gemm256<STATS>: 4 slots; col partials 16 slots.
// ---------------------------------------------------------------------------
__global__ __launch_bounds__(256) void stats_final(
    const float4* __restrict__ rp, const float4* __restrict__ cp,
    float2* __restrict__ row_tm, float2* __restrict__ col_tm,
    float* __restrict__ d1, float* __restrict__ d2)
{
    int idx = blockIdx.x * 256 + threadIdx.x;
    if (idx < Bn * NPn) {
        int b = idx >> 12, p = idx & (NPn - 1);
        float s = 0.f, q = 0.f, m = -3.4e38f;
#pragma unroll
        for (int i = 0; i < 4; i++) {
            float4 v = rp[((long)(b * 4 + i)) * NPn + p];
            s += v.x; q += v.y; m = fmaxf(m, v.z);
        }
        float mean = s * (1.0f / NCn);
        float var = fmaxf((q - (float)NCn * mean * mean) * (1.0f / (NCn - 1)), 0.0f);
        row_tm[idx] = make_float2(mean + sqrtf(var) * 0.125f, m);
        d1[idx] = 0.f;
    } else {
        int cidx = idx - Bn * NPn;
        int b = cidx >> 10, c = cidx & (NCn - 1);
        float s = 0.f, q = 0.f, m = -3.4e38f;
#pragma unroll
        for (int i = 0; i < 16; i++) {
            float4 v = cp[((long)(b * 16 + i)) * NCn + c];
            s += v.x; q += v.y; m = fmaxf(m, v.z);
        }
        float mean = s * (1.0f / NPn);
        float var = fmaxf((q - (float)NPn * mean * mean) * (1.0f / (NPn - 1)), 0.0f);
        col_tm[cidx] = make_float2(mean + sqrtf(var) * 0.125f, m);
        d2[cidx] = 0.f;
    }
}

// ---------------------------------------------------------------------------
// Merged masked softmax v2: one read of S produces A1u (row-major) and A2u
// (transposed); d1/d2 via atomics. 2 x 128-row halves -> T[64][133] = 34 KB
// -> 4 blocks/CU.
// ---------------------------------------------------------------------------
__global__ __launch_bounds__(256) void softmax_merged(
    const bf16* __restrict__ S, const float2* __restrict__ row_tm,
    const float2* __restrict__ col_tm, float* __restrict__ d1,
    float* __restrict__ d2, bf16* __restrict__ A1u, bf16* __restrict__ A2u)
{
    const int b = blockIdx.z, c0 = blockIdx.x * 64, p0 = blockIdx.y * 256;
    const int tid = threadIdx.x;
    const int rt = tid >> 3;          // 0..31 row within pass
    const int ct = (tid & 7) * 8;     // col offset, 8 cols per thread

    __shared__ float T[64][133];      // transposed e2 staging (1 half-tile)
    __shared__ float dw2[4][64];      // per-wave col-denom partials

    float2 ctm[8];
#pragma unroll
    for (int t = 0; t < 8; t++) ctm[t] = col_tm[b * NCn + c0 + ct + t];

    float d2acc[8];
#pragma unroll
    for (int t = 0; t < 8; t++) d2acc[t] = 0.f;

    for (int half = 0; half < 2; ++half) {
#pragma unroll
        for (int pass = 0; pass < 4; pass++) {
            const int p = p0 + half * 128 + pass * 32 + rt;
            const float2 rtm = row_tm[b * NPn + p];
            const long sidx = ((long)(b * NPn + p)) * NCn + c0 + ct;
            short8 sv = *(const short8*)(S + sidx);
            bf16 o1[8] __attribute__((aligned(16)));
            float e1s = 0.f;
#pragma unroll
            for (int t = 0; t < 8; t++) {
                float x = b2f(sv[t]);
                float e1 = (x >= rtm.x) ? __expf(x - rtm.y) : 0.0f;
                o1[t] = __float2bfloat16(e1);
                e1s += e1;
                float e2 = (x >= ctm[t].x) ? __expf(x - ctm[t].y) : 0.0f;
                d2acc[t] += e2;
                T[ct + t][pass * 32 + rt] = e2;
            }
            *(short8*)(A1u + sidx) = *(const short8*)o1;
            e1s += __shfl_xor(e1s, 1);
            e1s += __shfl_xor(e1s, 2);
            e1s += __shfl_xor(e1s, 4);
            if ((tid & 7) == 0) atomicAdd(&d1[b * NPn + p], e1s);
        }
        __syncthreads();
        // flush this half's A2u rows (transposed) from LDS
        {
            const int c = tid >> 2, pb = (tid & 3) * 32;
            bf16* dst = A2u + ((long)(b * NCn + c0 + c)) * NPn + p0 + half * 128 + pb;
#pragma unroll
            for (int u = 0; u < 4; u++) {
                bf16 tmp[8] __attribute__((aligned(16)));
#pragma unroll
                for (int w = 0; w < 8; w++)
                    tmp[w] = __float2bfloat16(T[c][pb + u * 8 + w]);
                *(short8*)(dst + u * 8) = *(const short8*)tmp;
            }
        }
        __syncthreads();   // T reusable for next half
    }

    // col denominators: reduce d2acc across rt within wave, then LDS
#pragma unroll
    for (int m = 8; m < 64; m <<= 1)
#pragma unroll
        for (int t = 0; t < 8; t++) d2acc[t] += __shfl_xor(d2acc[t], m);
    const int lane = tid & 63, wave = tid >> 6;
    if (lane < 8)
#pragma unroll
        for (int t = 0; t < 8; t++) dw2[wave][lane * 8 + t] = d2acc[t];
    __syncthreads();
    if (tid < 64)
        atomicAdd(&d2[b * NCn + c0 + tid],
                  dw2[0][tid] + dw2[1][tid] + dw2[2][tid] + dw2[3][tid]);
}

// ---------------------------------------------------------------------------
// Sum 4 split-K fp32 partials, scale row (b*NC+c) by 1/d2 -> bf16
// ---------------------------------------------------------------------------
__global__ __launch_bounds__(256) void reduce_scale_bf16(
    const float* __restrict__ Pp, const float* __restrict__ d2,
    bf16* __restrict__ out, long n4, long stride)
{
    long i = (long)blockIdx.x * 256 + threadIdx.x;
    if (i < n4) {
        float4 a = ((const float4*)Pp)[i];
#pragma unroll
        for (int s = 1; s < 4; s++) {
            float4 v = ((const float4*)(Pp + (long)s * stride))[i];
            a.x += v.x; a.y += v.y; a.z += v.z; a.w += v.w;
        }
        float inv = 1.0f / d2[i / (Dn / 4)];
        out[i * 4 + 0] = __float2bfloat16(a.x * inv);
        out[i * 4 + 1] = __float2bfloat16(a.y * inv);
        out[i * 4 + 2] = __float2bfloat16(a.z * inv);
        out[i * 4 + 3] = __float2bfloat16(a.w * inv);
    }
}

// ---------------------------------------------------------------------------
// fp32 [R x C] -> bf16 row-major copy AND bf16 [C x R] transpose, batched z.
// Round-9 v2: flat 256-thread block; float4 coalesced loads; BOTH outputs
// written as 16B short8 stores (was 2B scalar -> 64B segments at half rate).
// LDS tile [32][33] f32: load 8 lanes/row conflict-free; both read patterns
// 2-way aliased only (free, m136).
// ---------------------------------------------------------------------------
__global__ __launch_bounds__(256) void cvt_both(
    const float* __restrict__ in, bf16* __restrict__ out_rm,
    bf16* __restrict__ out_t, int R, int C)
{
    __shared__ float tile[32][33];
    const long boff = (long)blockIdx.z * (long)R * C;
    in += boff; out_rm += boff; out_t += boff;
    const int c0 = blockIdx.x * 32, r0 = blockIdx.y * 32;
    const int tid = threadIdx.x;

    // load 32x32 f32: thread t -> row t>>3, cols (t&7)*4 (float4, 128B/row)
    {
        const int rr = tid >> 3, cc = (tid & 7) * 4;
        float4 v = *(const float4*)(in + (long)(r0 + rr) * C + c0 + cc);
        tile[rr][cc + 0] = v.x;
        tile[rr][cc + 1] = v.y;
        tile[rr][cc + 2] = v.z;
        tile[rr][cc + 3] = v.w;
    }
    __syncthreads();

    if (tid < 128) {
        // out_rm: thread t -> row t>>2, 8 cols at (t&3)*8 (short8 = 16B)
        const int rr = tid >> 2, ch = (tid & 3) * 8;
        bf16 tmp[8] __attribute__((aligned(16)));
#pragma unroll
        for (int w = 0; w < 8; w++)
            tmp[w] = __float2bfloat16(tile[rr][ch + w]);
        *(short8*)(out_rm + (long)(r0 + rr) * C + c0 + ch) = *(const short8*)tmp;
    } else {
        // out_t: thread t2 -> out-row (c0 + t2>>2), 8 cols at (t2&3)*8
        const int t2 = tid - 128;
        const int cc2 = t2 >> 2, ch = (t2 & 3) * 8;
        bf16 tmp[8] __attribute__((aligned(16)));
#pragma unroll
        for (int w = 0; w < 8; w++)
            tmp[w] = __float2bfloat16(tile[ch + w][cc2]);
        *(short8*)(out_t + (long)(c0 + cc2) * R + r0 + ch) = *(const short8*)tmp;
    }
}

// ---------------------------------------------------------------------------
extern "C" void kernel_launch(void* const* d_in, const int* in_sizes, int n_in,
                              void* d_out, int out_size, void* d_ws, size_t ws_size,
                              hipStream_t stream)
{
    const float* Xp = (const float*)d_in[0];  // [4,4096,512]
    const float* Xc = (const float*)d_in[1];  // [4,1024,512]
    float* out = (float*)d_out;               // [4,4096,1024]

    constexpr int B = Bn, NP = NPn, NC = NCn, D = Dn;
    constexpr float SCALE = 0.044194173824159216f;  // 1/sqrt(512)

    // workspace layout (bytes), ~164 MB
    char* ws = (char*)d_ws;
    bf16*   Qp     = (bf16*)(ws);                   // 16.78 MB [B,NP,D]
    bf16*   Kc     = (bf16*)(ws + 16777216);        //  4.19 MB [B,NC,D]
    bf16*   KcT    = (bf16*)(ws + 20971520);        //  4.19 MB [B,D,NC]
    bf16*   XpT    = (bf16*)(ws + 25165824);        // 16.78 MB [B,D,NP]
    bf16*   S      = (bf16*)(ws + 41943040);        // 33.55 MB [B,NP,NC]; later Hp overlays
    bf16*   A1u    = (bf16*)(ws + 75497472);        // 33.55 MB [B,NP,NC]
    bf16*   A2u    = (bf16*)(ws + 109051904);       // 33.55 MB [B,NC,NP]; rp/cp overlay pre-softmax
    bf16*   H1u    = (bf16*)(ws + 142606336);       // 16.78 MB [B,NP,D]
    bf16*   H2     = (bf16*)(ws + 159383552);       //  4.19 MB [B,NC,D]
    float2* row_tm = (float2*)(ws + 163577856);     // 128 KB  [B*NP]
    float2* col_tm = (float2*)(ws + 163708928);     //  32 KB  [B*NC]
    float*  d1     = (float*)(ws + 163741696);      //  64 KB  [B*NP]
    float*  d2     = (float*)(ws + 163807232);      //  16 KB  [B*NC]
    float4* rp     = (float4*)A2u;                  //  1.05 MB [B*4,NP]
    float4* cp     = (float4*)(ws + 109051904 + 4194304);  // 1.05 MB [B*16,NC]
    float*  Hp     = (float*)S;                     // split-K partials [4][B,NC,D] fp32 (S dead)

    // 1-2: convert + transpose inputs (one read of fp32 each)
    cvt_both<<<dim3(D / 32, NP / 32, B), dim3(256), 0, stream>>>(Xp, Qp, XpT, NP, D);
    cvt_both<<<dim3(D / 32, NC / 32, B), dim3(256), 0, stream>>>(Xc, Kc, KcT, NC, D);

    // 3: S = Qp*Kc^T*scale (bf16) -- 256x256 8-phase, fused row/col stats
    gemm256<bf16, false, true><<<dim3(NC / 256, NP / 256, B), dim3(512), 0, stream>>>(
        Qp, Kc, S, NP, NC, D, (long)NP * D, (long)NC * D, (long)NP * NC,
        SCALE, B, nullptr, rp, cp);
    // 4: finalize thr/max (rows: 4 partials, cols: 16); zero denoms
    stats_final<<<dim3((B * NP + B * NC) / 256), dim3(256), 0, stream>>>(
        rp, cp, row_tm, col_tm, d1, d2);
    // 5: merged softmax -> A1u + A2u (transposed), denoms via atomics
    softmax_merged<<<dim3(NC / 64, NP / 256, B), dim3(256), 0, stream>>>(
        S, row_tm, col_tm, d1, d2, A1u, A2u);
    // 6: H1u = A1u * Kc  [B,NP,D] bf16 -- 256x128 dense-2-phase
    gemm256n128<bf16, false><<<dim3(D / 128, NP / 256, B), dim3(512), 0, stream>>>(
        A1u, KcT, H1u, NP, D, NC, (long)NP * NC, (long)D * NC, (long)NP * D,
        1.0f, B, 1, nullptr);
    // 7: Hp = A2u * Xp partials [4][B,NC,D] fp32, 4-way split-K
    gemm256n128<float, false><<<dim3(D / 128, NC / 256, 4 * B), dim3(512), 0, stream>>>(
        A2u, XpT, Hp, NC, D, NP, (long)NC * NP, (long)D * NP, (long)NC * D,
        1.0f, B, 4, nullptr);
    // 8: H2 = sum(Hp) / d2 -> bf16
    {
        long n = (long)B * NC * D;
        reduce_scale_bf16<<<dim3((n / 4 + 255) / 256), dim3(256), 0, stream>>>(
            Hp, d2, H2, n / 4, n);
    }
    // 9: out = diag(1/d1) * H1u * H2^T   [B,NP,NC] fp32 -- 256x256 8-phase
    gemm256<float, true, false><<<dim3(NC / 256, NP / 256, B), dim3(512), 0, stream>>>(
        H1u, H2, out, NP, NC, D, (long)NP * D, (long)NC * D, (long)NP * NC,
        1.0f, B, d1, nullptr, nullptr);
}

// Round 10
// 244.027 us; speedup vs baseline: 1.0739x; 1.0359x over previous
//
#include <hip/hip_runtime.h>
#include <hip/hip_bf16.h>

using bf16 = __hip_bfloat16;
typedef __attribute__((ext_vector_type(8))) short short8;   // 8 bf16 (4 VGPRs)
typedef __attribute__((ext_vector_type(4))) float floatx4;  // MFMA C/D frag

#define NPn 4096
#define NCn 1024
#define Dn  512
#define Bn  4

__device__ __forceinline__ float b2f(short s) {
    union { unsigned u; float f; } cv;
    cv.u = ((unsigned)(unsigned short)s) << 16;
    return cv.f;
}

// ---------------------------------------------------------------------------
// async global->LDS, 16B per lane. LDS dest = (wave-uniform base) + lane*16B.
// ---------------------------------------------------------------------------
__device__ __forceinline__ void async_copy16(const bf16* g, bf16* l) {
    __builtin_amdgcn_global_load_lds(
        (const __attribute__((address_space(1))) unsigned int*)g,
        (__attribute__((address_space(3))) unsigned int*)l,
        16, 0, 0);
}

#define SBAR()  __builtin_amdgcn_s_barrier()
#define SCHED0() __builtin_amdgcn_sched_barrier(0)

// ---------------------------------------------------------------------------
// 256x256-tile 8-phase GEMM (T2+T3+T4+T5 port of the m201 template).
// Round-7/9 verified state (best: 252.8 us total). Used for steps 3 and 9.
// 512 threads = 8 waves as 2(M) x 4(N); per-wave output 128x64 = acc[8][4].
// LDS [buf][ks][256][32] bf16, 128 KB, double buffered.
// STATS: fused row/col stat partials in the epilogue.
// vmcnt ledger: prologue 8 ops, vmcnt(4); P0/P1/P2/P3 keep 6-8 in flight,
// vmcnt(4) at P1/P3; never 0 in main loop; last tile peeled.
// ---------------------------------------------------------------------------
template <typename OutT, bool RS, bool STATS>
__global__ __launch_bounds__(512) void gemm256(
    const bf16* __restrict__ A, const bf16* __restrict__ B, OutT* __restrict__ C,
    int M, int N, int K, long strideA, long strideB, long strideC,
    float scale, int nbat, const float* __restrict__ rsc,
    float4* __restrict__ rp, float4* __restrict__ cp)
{
    const int z = blockIdx.z;
    const int b = z % nbat;
    A += (long)b * strideA;
    B += (long)b * strideB;
    C += (long)z * strideC;

    // XCD-aware bijective swizzle of the (bx,by) plane (m204).
    const int nwg = gridDim.x * gridDim.y;
    const int orig = blockIdx.y * gridDim.x + blockIdx.x;
    const int q = nwg >> 3, r = nwg & 7;
    const int xcd = orig & 7, pos = orig >> 3;
    const int nid = (xcd < r ? xcd * (q + 1) : r * (q + 1) + (xcd - r) * q) + pos;
    const int bm = (nid / gridDim.x) * 256;
    const int bn = (nid % gridDim.x) * 256;

    const int tid = threadIdx.x;
    const int lane = tid & 63;
    const int wave = tid >> 6;                 // 0..7
    const int wm2 = (wave >> 2) * 128;         // wave's M offset (0/128)
    const int wn2 = (wave & 3) * 64;           // wave's N offset (0/64/128/192)
    const int mrow = lane & 15;
    const int g = lane >> 4;                   // k-chunk group 0..3

    __shared__ bf16 Asl[2][2][256][32];        // [buf][ks][row][col] 64 KB
    __shared__ bf16 Bsl[2][2][256][32];        // 64 KB

    floatx4 acc[8][4];
#pragma unroll
    for (int i = 0; i < 8; i++)
#pragma unroll
        for (int j = 0; j < 4; j++) acc[i][j] = (floatx4)(0.0f);

    const int s0 = wave * 64 + lane;
    const int sr = s0 >> 2, sc = s0 & 3;
    auto stageA = [&](int kb, int ks, int buf) {
        const int cg = (sc ^ (sr & 3)) * 8;
        const bf16* src0 = A + (long)(bm + sr) * K + kb + ks * 32 + cg;
        const bf16* src1 = A + (long)(bm + sr + 128) * K + kb + ks * 32 + cg;
        bf16* base = &Asl[buf][ks][0][0];
        async_copy16(src0, base + wave * 512);
        async_copy16(src1, base + 4096 + wave * 512);
    };
    auto stageB = [&](int kb, int ks, int buf) {
        const int cg = (sc ^ (sr & 3)) * 8;
        const bf16* src0 = B + (long)(bn + sr) * K + kb + ks * 32 + cg;
        const bf16* src1 = B + (long)(bn + sr + 128) * K + kb + ks * 32 + cg;
        bf16* base = &Bsl[buf][ks][0][0];
        async_copy16(src0, base + wave * 512);
        async_copy16(src1, base + 4096 + wave * 512);
    };
    auto ldA = [&](int buf, int ks, int mi) -> short8 {
        const int row = wm2 + mi * 16 + mrow;
        const int cc = (g ^ (row & 3)) * 8;
        return *(const short8*)(&Asl[buf][ks][row][cc]);
    };
    auto ldB = [&](int buf, int ks, int ni) -> short8 {
        const int row = wn2 + ni * 16 + mrow;
        const int cc = (g ^ (row & 3)) * 8;
        return *(const short8*)(&Bsl[buf][ks][row][cc]);
    };

#define MFMA_GRP(MS)                                                          \
    do {                                                                      \
        _Pragma("unroll") for (int i = 0; i < 4; i++)                         \
            _Pragma("unroll") for (int j = 0; j < 4; j++)                     \
                acc[(MS) + i][j] = __builtin_amdgcn_mfma_f32_16x16x32_bf16(   \
                    a[i], bb[j], acc[(MS) + i][j], 0, 0, 0);                  \
    } while (0)

    const int nt = K / 64;
    stageA(0, 0, 0); stageB(0, 0, 0);
    stageA(0, 1, 0); stageB(0, 1, 0);
    asm volatile("s_waitcnt vmcnt(4)" ::: "memory");
    SBAR(); SCHED0();

    int cur = 0;
    for (int t = 0; t < nt - 1; ++t) {
        const int nxt = cur ^ 1;
        const int kb1 = (t + 1) * 64;
        short8 a[4], bb[4];
        // ---- P0 ----
#pragma unroll
        for (int i = 0; i < 4; i++) a[i] = ldA(cur, 0, i);
#pragma unroll
        for (int j = 0; j < 4; j++) bb[j] = ldB(cur, 0, j);
        stageA(kb1, 0, nxt);
        SBAR();
        asm volatile("s_waitcnt lgkmcnt(0)" ::: "memory");
        SCHED0();
        __builtin_amdgcn_s_setprio(1);
        MFMA_GRP(0);
        __builtin_amdgcn_s_setprio(0);
        SCHED0(); SBAR(); SCHED0();
        // ---- P1 ----
#pragma unroll
        for (int i = 0; i < 4; i++) a[i] = ldA(cur, 0, 4 + i);
        stageB(kb1, 0, nxt);
        asm volatile("s_waitcnt vmcnt(4)" ::: "memory");   // t's khi landed
        SBAR();
        asm volatile("s_waitcnt lgkmcnt(0)" ::: "memory");
        SCHED0();
        __builtin_amdgcn_s_setprio(1);
        MFMA_GRP(4);
        __builtin_amdgcn_s_setprio(0);
        SCHED0(); SBAR(); SCHED0();
        // ---- P2 ----
#pragma unroll
        for (int i = 0; i < 4; i++) a[i] = ldA(cur, 1, i);
#pragma unroll
        for (int j = 0; j < 4; j++) bb[j] = ldB(cur, 1, j);
        stageA(kb1, 1, nxt);
        SBAR();
        asm volatile("s_waitcnt lgkmcnt(0)" ::: "memory");
        SCHED0();
        __builtin_amdgcn_s_setprio(1);
        MFMA_GRP(0);
        __builtin_amdgcn_s_setprio(0);
        SCHED0(); SBAR(); SCHED0();
        // ---- P3 ----
#pragma unroll
        for (int i = 0; i < 4; i++) a[i] = ldA(cur, 1, 4 + i);
        stageB(kb1, 1, nxt);
        asm volatile("s_waitcnt vmcnt(4)" ::: "memory");   // t+1's klo landed
        SBAR();
        asm volatile("s_waitcnt lgkmcnt(0)" ::: "memory");
        SCHED0();
        __builtin_amdgcn_s_setprio(1);
        MFMA_GRP(4);
        __builtin_amdgcn_s_setprio(0);
        SCHED0(); SBAR(); SCHED0();
        cur = nxt;
    }
    // ---- last tile (no staging) ----
    {
        short8 a[4], bb[4];
#pragma unroll
        for (int i = 0; i < 4; i++) a[i] = ldA(cur, 0, i);
#pragma unroll
        for (int j = 0; j < 4; j++) bb[j] = ldB(cur, 0, j);
        SBAR();
        asm volatile("s_waitcnt lgkmcnt(0)" ::: "memory");
        SCHED0();
        MFMA_GRP(0);
        SCHED0(); SBAR(); SCHED0();
#pragma unroll
        for (int i = 0; i < 4; i++) a[i] = ldA(cur, 0, 4 + i);
        asm volatile("s_waitcnt vmcnt(0)" ::: "memory");   // its khi landed
        SBAR();
        asm volatile("s_waitcnt lgkmcnt(0)" ::: "memory");
        SCHED0();
        MFMA_GRP(4);
        SCHED0(); SBAR(); SCHED0();
#pragma unroll
        for (int i = 0; i < 4; i++) a[i] = ldA(cur, 1, i);
#pragma unroll
        for (int j = 0; j < 4; j++) bb[j] = ldB(cur, 1, j);
        asm volatile("s_waitcnt lgkmcnt(0)" ::: "memory");
        SCHED0();
        MFMA_GRP(0);
#pragma unroll
        for (int i = 0; i < 4; i++) a[i] = ldA(cur, 1, 4 + i);
        asm volatile("s_waitcnt lgkmcnt(0)" ::: "memory");
        SCHED0();
        MFMA_GRP(4);
    }
#undef MFMA_GRP

    const int crow = (lane >> 4) * 4;
    const int ccol = lane & 15;

    if constexpr (STATS) {
        __syncthreads();
        float* rst = (float*)&Asl[0][0][0][0];   // [nw(4)][plane(3)][256 rows]
        float* cst = (float*)&Bsl[0][0][0][0];   // [mw(2)][plane(3)][256 cols]
        const int nw = wave & 3, mw = wave >> 2;
        const int rg = lane >> 4, cl = lane & 15;

        float cs[4], cq[4], cm[4];
#pragma unroll
        for (int j = 0; j < 4; j++) { cs[j] = 0.f; cq[j] = 0.f; cm[j] = -3.4e38f; }

#pragma unroll
        for (int i = 0; i < 8; i++) {
            float rs[4], rq[4], rm[4];
#pragma unroll
            for (int r2 = 0; r2 < 4; r2++) { rs[r2] = 0.f; rq[r2] = 0.f; rm[r2] = -3.4e38f; }
#pragma unroll
            for (int j = 0; j < 4; j++)
#pragma unroll
                for (int r2 = 0; r2 < 4; r2++) {
                    float v = acc[i][j][r2] * scale;
                    rs[r2] += v; rq[r2] += v * v; rm[r2] = fmaxf(rm[r2], v);
                    cs[j] += v; cq[j] += v * v; cm[j] = fmaxf(cm[j], v);
                }
#pragma unroll
            for (int m = 1; m < 16; m <<= 1)
#pragma unroll
                for (int r2 = 0; r2 < 4; r2++) {
                    rs[r2] += __shfl_xor(rs[r2], m);
                    rq[r2] += __shfl_xor(rq[r2], m);
                    rm[r2] = fmaxf(rm[r2], __shfl_xor(rm[r2], m));
                }
            if (cl == 0) {
#pragma unroll
                for (int r2 = 0; r2 < 4; r2++) {
                    int row = wm2 + i * 16 + rg * 4 + r2;
                    rst[nw * 768 + row] = rs[r2];
                    rst[nw * 768 + 256 + row] = rq[r2];
                    rst[nw * 768 + 512 + row] = rm[r2];
                }
            }
        }
#pragma unroll
        for (int m = 16; m < 64; m <<= 1)
#pragma unroll
            for (int j = 0; j < 4; j++) {
                cs[j] += __shfl_xor(cs[j], m);
                cq[j] += __shfl_xor(cq[j], m);
                cm[j] = fmaxf(cm[j], __shfl_xor(cm[j], m));
            }
        if (rg == 0) {
#pragma unroll
            for (int j = 0; j < 4; j++) {
                int col = wn2 + j * 16 + cl;
                cst[mw * 768 + col] = cs[j];
                cst[mw * 768 + 256 + col] = cq[j];
                cst[mw * 768 + 512 + col] = cm[j];
            }
        }
        __syncthreads();
        if (tid < 256) {
            float s = 0.f, qq = 0.f, m = -3.4e38f;
#pragma unroll
            for (int w = 0; w < 4; w++) {
                s += rst[w * 768 + tid];
                qq += rst[w * 768 + 256 + tid];
                m = fmaxf(m, rst[w * 768 + 512 + tid]);
            }
            rp[((long)(b * 4 + (bn >> 8))) * M + bm + tid] = make_float4(s, qq, m, 0.f);
            float s2 = cst[tid] + cst[768 + tid];
            float q2 = cst[256 + tid] + cst[768 + 256 + tid];
            float m2 = fmaxf(cst[512 + tid], cst[768 + 512 + tid]);
            cp[((long)(b * 16 + (bm >> 8))) * N + bn + tid] = make_float4(s2, q2, m2, 0.f);
        }
    }

    // epilogue: C store (scalar — fire-and-forget)
    float inv_[8][4];
#pragma unroll
    for (int i = 0; i < 8; i++)
#pragma unroll
        for (int r2 = 0; r2 < 4; r2++) {
            if constexpr (RS)
                inv_[i][r2] = 1.0f / rsc[(long)b * M + bm + wm2 + i * 16 + crow + r2];
            else
                inv_[i][r2] = 1.0f;
        }
#pragma unroll
    for (int i = 0; i < 8; i++) {
#pragma unroll
        for (int j = 0; j < 4; j++) {
#pragma unroll
            for (int r2 = 0; r2 < 4; r2++) {
                long rr = bm + wm2 + i * 16 + crow + r2;
                long cc = bn + wn2 + j * 16 + ccol;
                float v = acc[i][j][r2] * scale * inv_[i][r2];
                if constexpr (__is_same(OutT, float))
                    C[rr * (long)N + cc] = v;
                else
                    C[rr * (long)N + cc] = __float2bfloat16(v);
            }
        }
    }
}

// ---------------------------------------------------------------------------
// Round-10: FUSED steps 6+7 in one launch. Both depend only on softmax and
// are mutually independent; previously serial, each at ~1 block/CU with
// barrier-lockstep drains fully exposed. This kernel: 128x128 tile,
// dense-2-phase (16 MFMA + 8 ds_read_b128 per phase), 4 waves (2Mx2N),
// LDS A[2][2][128][32]+B[2][2][128][32] = 64 KB -> 2 blocks/CU, so a CU's
// second resident block covers the first one's barrier/load stalls.
//
// Grid: 1024 blocks 1-D. XCD-swizzle (bijective, 1024%8==0) then parity:
// even nid -> task6 (H1u = A1u x KcT^T, f=nid>>1 in 0..511), odd -> task7
// (Hp = A2u x XpT^T, 4-way split-K). Adjacent nids alternate tasks so a
// CU's two resident blocks are typically one of each.
//
//   task6: M=NP rows of A1u[b], B=KcT[b] (row stride NC), C=H1u bf16,
//          bx=f&3 (bn), by=(f>>2)&31 (bm over 4096), b=f>>7, K=klen=1024.
//   task7: M=NC rows of A2u[b], B=XpT[b] (row stride NP), C=Hp slot
//          (s*4+b) fp32, bx=f&3, by=(f>>2)&7, zz=f>>5, b=zz&3, s=zz>>2,
//          Kfull=4096, klen=1024, k0=s*1024.
// N=512 and nt=klen/64=16 for both tasks.
//
// Per-thread vmcnt ledger (stageA=2 ops, stageB=2 ops per k-half; in-order
// retire): prologue stages klo+khi = 8 ops, vmcnt(4) -> klo landed, khi 4
// in flight. P0(t): +4 (klo t+1) = 8; vmcnt(4) retires t's khi -> P1 reads
// safe. P1(t): +4 (khi t+1) = 8; vmcnt(4) retires t+1's klo -> next P0
// safe. Never 0 in main loop (T4). Last tile peeled: klo already landed
// (prev P1's vmcnt(4)); vmcnt(0) before its khi reads.
// Buffer edge: stage(t+1)->nxt issues after P1(t-1)'s closing SBAR, by
// which time all waves' tile-(t-1) ds_reads completed (per-wave lgkm0
// precedes that barrier) -> safe to overwrite (R6 proof, refcheck'd).
// ---------------------------------------------------------------------------
__global__ __launch_bounds__(256) void gemm128_fused(
    const bf16* __restrict__ A1u, const bf16* __restrict__ KcT,
    bf16* __restrict__ H1u,
    const bf16* __restrict__ A2u, const bf16* __restrict__ XpT,
    float* __restrict__ Hp)
{
    const int nwg = gridDim.x;                 // 1024
    const int orig = blockIdx.x;
    const int nid = (orig & 7) * (nwg >> 3) + (orig >> 3);   // bijective
    const int task = nid & 1;
    const int f = nid >> 1;                    // 0..511

    const bf16* A;
    const bf16* B;
    bf16* Cb = nullptr;
    float* Cf = nullptr;
    int bm, bn, Kfull, k0;
    if (task == 0) {
        const int bx = f & 3, by = (f >> 2) & 31, b = f >> 7;
        A = A1u + (long)b * NPn * NCn;
        B = KcT + (long)b * Dn * NCn;
        Cb = H1u + (long)b * NPn * Dn;
        bm = by * 128; bn = bx * 128;
        Kfull = NCn; k0 = 0;
    } else {
        const int bx = f & 3, by = (f >> 2) & 7, zz = f >> 5;
        const int b = zz & 3, s = zz >> 2;
        A = A2u + (long)b * NCn * NPn;
        B = XpT + (long)b * Dn * NPn;
        Cf = Hp + (long)(s * 4 + b) * NCn * Dn;
        bm = by * 128; bn = bx * 128;
        Kfull = NPn; k0 = s * (NPn / 4);
    }
    const int klen = 1024;                     // both tasks
    const int nt = klen / 64;                  // 16

    const int tid = threadIdx.x;
    const int lane = tid & 63;
    const int wave = tid >> 6;                 // 0..3
    const int wm2 = (wave >> 1) * 64;          // M offset (0/64)
    const int wn2 = (wave & 1) * 64;           // N offset (0/64)
    const int mrow = lane & 15;
    const int g = lane >> 4;                   // k-chunk group 0..3

    __shared__ bf16 Asl[2][2][128][32];        // 32 KB
    __shared__ bf16 Bsl[2][2][128][32];        // 32 KB

    floatx4 acc[4][4];
#pragma unroll
    for (int i = 0; i < 4; i++)
#pragma unroll
        for (int j = 0; j < 4; j++) acc[i][j] = (floatx4)(0.0f);

    // staging: 128x32 bf16 half = 512 x 16B slots; 256 threads x 2 ops.
    // slot -> row sr = slot>>2, chunk sc = slot&3; LDS dest linear.
    const int sr0 = tid >> 2, sc0 = tid & 3;           // slots 0..255
    const int sr1 = (tid + 256) >> 2;                  // slots 256..511
    auto stageA = [&](int kb, int ks, int buf) {
        const int cg0 = (sc0 ^ (sr0 & 3)) * 8;
        const int cg1 = (sc0 ^ (sr1 & 3)) * 8;         // sc same, sr+64
        const bf16* src0 = A + (long)(bm + sr0) * Kfull + kb + ks * 32 + cg0;
        const bf16* src1 = A + (long)(bm + sr1) * Kfull + kb + ks * 32 + cg1;
        bf16* base = &Asl[buf][ks][0][0];
        async_copy16(src0, base + tid * 8);            // 8 bf16 = 16B
        async_copy16(src1, base + 2048 + tid * 8);
    };
    auto stageB = [&](int kb, int ks, int buf) {
        const int cg0 = (sc0 ^ (sr0 & 3)) * 8;
        const int cg1 = (sc0 ^ (sr1 & 3)) * 8;
        const bf16* src0 = B + (long)(bn + sr0) * Kfull + kb + ks * 32 + cg0;
        const bf16* src1 = B + (long)(bn + sr1) * Kfull + kb + ks * 32 + cg1;
        bf16* base = &Bsl[buf][ks][0][0];
        async_copy16(src0, base + tid * 8);
        async_copy16(src1, base + 2048 + tid * 8);
    };
    auto ldA = [&](int buf, int ks, int mi) -> short8 {
        const int row = wm2 + mi * 16 + mrow;
        const int cc = (g ^ (row & 3)) * 8;
        return *(const short8*)(&Asl[buf][ks][row][cc]);
    };
    auto ldB = [&](int buf, int ks, int ni) -> short8 {
        const int row = wn2 + ni * 16 + mrow;
        const int cc = (g ^ (row & 3)) * 8;
        return *(const short8*)(&Bsl[buf][ks][row][cc]);
    };

#define MFMA_GRP16()                                                          \
    do {                                                                      \
        _Pragma("unroll") for (int i = 0; i < 4; i++)                         \
            _Pragma("unroll") for (int j = 0; j < 4; j++)                     \
                acc[i][j] = __builtin_amdgcn_mfma_f32_16x16x32_bf16(          \
                    a[i], bb[j], acc[i][j], 0, 0, 0);                         \
    } while (0)

    stageA(k0, 0, 0); stageB(k0, 0, 0);
    stageA(k0, 1, 0); stageB(k0, 1, 0);
    asm volatile("s_waitcnt vmcnt(4)" ::: "memory");
    SBAR(); SCHED0();

    int cur = 0;
    for (int t = 0; t < nt - 1; ++t) {
        const int nxt = cur ^ 1;
        const int kb1 = k0 + (t + 1) * 64;
        short8 a[4], bb[4];
        // ---- P0: k-half 0 ----
#pragma unroll
        for (int i = 0; i < 4; i++) a[i] = ldA(cur, 0, i);
#pragma unroll
        for (int j = 0; j < 4; j++) bb[j] = ldB(cur, 0, j);
        stageA(kb1, 0, nxt);
        stageB(kb1, 0, nxt);
        asm volatile("s_waitcnt vmcnt(4)" ::: "memory");   // t's khi landed
        SBAR();
        asm volatile("s_waitcnt lgkmcnt(0)" ::: "memory");
        SCHED0();
        __builtin_amdgcn_s_setprio(1);
        MFMA_GRP16();
        __builtin_amdgcn_s_setprio(0);
        SCHED0(); SBAR(); SCHED0();
        // ---- P1: k-half 1 ----
#pragma unroll
        for (int i = 0; i < 4; i++) a[i] = ldA(cur, 1, i);
#pragma unroll
        for (int j = 0; j < 4; j++) bb[j] = ldB(cur, 1, j);
        stageA(kb1, 1, nxt);
        stageB(kb1, 1, nxt);
        asm volatile("s_waitcnt vmcnt(4)" ::: "memory");   // t+1's klo landed
        SBAR();
        asm volatile("s_waitcnt lgkmcnt(0)" ::: "memory");
        SCHED0();
        __builtin_amdgcn_s_setprio(1);
        MFMA_GRP16();
        __builtin_amdgcn_s_setprio(0);
        SCHED0(); SBAR(); SCHED0();
        cur = nxt;
    }
    // ---- last tile (no staging) ----
    {
        short8 a[4], bb[4];
#pragma unroll
        for (int i = 0; i < 4; i++) a[i] = ldA(cur, 0, i);
#pragma unroll
        for (int j = 0; j < 4; j++) bb[j] = ldB(cur, 0, j);
        asm volatile("s_waitcnt vmcnt(0)" ::: "memory");   // its khi landed
        SBAR();
        asm volatile("s_waitcnt lgkmcnt(0)" ::: "memory");
        SCHED0();
        __builtin_amdgcn_s_setprio(1);
        MFMA_GRP16();
        __builtin_amdgcn_s_setprio(0);
        SCHED0(); SBAR(); SCHED0();
#pragma unroll
        for (int i = 0; i < 4; i++) a[i] = ldA(cur, 1, i);
#pragma unroll
        for (int j = 0; j < 4; j++) bb[j] = ldB(cur, 1, j);
        asm volatile("s_waitcnt lgkmcnt(0)" ::: "memory");
        SCHED0();
        MFMA_GRP16();
    }
#undef MFMA_GRP16

    // epilogue: scalar stores, N=512 both tasks
    const int crow = (lane >> 4) * 4;
    const int ccol = lane & 15;
#pragma unroll
    for (int i = 0; i < 4; i++) {
#pragma unroll
        for (int j = 0; j < 4; j++) {
#pragma unroll
            for (int r2 = 0; r2 < 4; r2++) {
                long rr = bm + wm2 + i * 16 + crow + r2;
                long cc = bn + wn2 + j * 16 + ccol;
                float v = acc[i][j][r2];
                if (task == 0)
                    Cb[rr * (long)Dn + cc] = __float2bfloat16(v);
                else
                    Cf[rr * (long)Dn + cc] = v;
            }
        }
    }
}

// ---------------------------------------------------------------------------
// Finalize stats; thr = mean + std(ddof=1)/8. Also zeros d1/d2.
// Row partials from gemm256<STATS>: 4 slots; col partials 16 slots.
// ---------------------------------------------------------------------------
__global__ __launch_bounds__(256) void stats_final(
    const float4* __restrict__ rp, const float4* __restrict__ cp,
    float2* __restrict__ row_tm, float2* __restrict__ col_tm,
    float* __restrict__ d1, float* __restrict__ d2)
{
    int idx = blockIdx.x * 256 + threadIdx.x;
    if (idx < Bn * NPn) {
        int b = idx >> 12, p = idx & (NPn - 1);
        float s = 0.f, q = 0.f, m = -3.4e38f;
#pragma unroll
        for (int i = 0; i < 4; i++) {
            float4 v = rp[((long)(b * 4 + i)) * NPn + p];
            s += v.x; q += v.y; m = fmaxf(m, v.z);
        }
        float mean = s * (1.0f / NCn);
        float var = fmaxf((q - (float)NCn * mean * mean) * (1.0f / (NCn - 1)), 0.0f);
        row_tm[idx] = make_float2(mean + sqrtf(var) * 0.125f, m);
        d1[idx] = 0.f;
    } else {
        int cidx = idx - Bn * NPn;
        int b = cidx >> 10, c = cidx & (NCn - 1);
        float s = 0.f, q = 0.f, m = -3.4e38f;
#pragma unroll
        for (int i = 0; i < 16; i++) {
            float4 v = cp[((long)(b * 16 + i)) * NCn + c];
            s += v.x; q += v.y; m = fmaxf(m, v.z);
        }
        float mean = s * (1.0f / NPn);
        float var = fmaxf((q - (float)NPn * mean * mean) * (1.0f / (NPn - 1)), 0.0f);
        col_tm[cidx] = make_float2(mean + sqrtf(var) * 0.125f, m);
        d2[cidx] = 0.f;
    }
}

// ---------------------------------------------------------------------------
// Merged masked softmax v2: one read of S produces A1u (row-major) and A2u
// (transposed); d1/d2 via atomics. 2 x 128-row halves -> T[64][133] = 34 KB
// -> 4 blocks/CU.
// ---------------------------------------------------------------------------
__global__ __launch_bounds__(256) void softmax_merged(
    const bf16* __restrict__ S, const float2* __restrict__ row_tm,
    const float2* __restrict__ col_tm, float* __restrict__ d1,
    float* __restrict__ d2, bf16* __restrict__ A1u, bf16* __restrict__ A2u)
{
    const int b = blockIdx.z, c0 = blockIdx.x * 64, p0 = blockIdx.y * 256;
    const int tid = threadIdx.x;
    const int rt = tid >> 3;          // 0..31 row within pass
    const int ct = (tid & 7) * 8;     // col offset, 8 cols per thread

    __shared__ float T[64][133];      // transposed e2 staging (1 half-tile)
    __shared__ float dw2[4][64];      // per-wave col-denom partials

    float2 ctm[8];
#pragma unroll
    for (int t = 0; t < 8; t++) ctm[t] = col_tm[b * NCn + c0 + ct + t];

    float d2acc[8];
#pragma unroll
    for (int t = 0; t < 8; t++) d2acc[t] = 0.f;

    for (int half = 0; half < 2; ++half) {
#pragma unroll
        for (int pass = 0; pass < 4; pass++) {
            const int p = p0 + half * 128 + pass * 32 + rt;
            const float2 rtm = row_tm[b * NPn + p];
            const long sidx = ((long)(b * NPn + p)) * NCn + c0 + ct;
            short8 sv = *(const short8*)(S + sidx);
            bf16 o1[8] __attribute__((aligned(16)));
            float e1s = 0.f;
#pragma unroll
            for (int t = 0; t < 8; t++) {
                float x = b2f(sv[t]);
                float e1 = (x >= rtm.x) ? __expf(x - rtm.y) : 0.0f;
                o1[t] = __float2bfloat16(e1);
                e1s += e1;
                float e2 = (x >= ctm[t].x) ? __expf(x - ctm[t].y) : 0.0f;
                d2acc[t] += e2;
                T[ct + t][pass * 32 + rt] = e2;
            }
            *(short8*)(A1u + sidx) = *(const short8*)o1;
            e1s += __shfl_xor(e1s, 1);
            e1s += __shfl_xor(e1s, 2);
            e1s += __shfl_xor(e1s, 4);
            if ((tid & 7) == 0) atomicAdd(&d1[b * NPn + p], e1s);
        }
        __syncthreads();
        // flush this half's A2u rows (transposed) from LDS
        {
            const int c = tid >> 2, pb = (tid & 3) * 32;
            bf16* dst = A2u + ((long)(b * NCn + c0 + c)) * NPn + p0 + half * 128 + pb;
#pragma unroll
            for (int u = 0; u < 4; u++) {
                bf16 tmp[8] __attribute__((aligned(16)));
#pragma unroll
                for (int w = 0; w < 8; w++)
                    tmp[w] = __float2bfloat16(T[c][pb + u * 8 + w]);
                *(short8*)(dst + u * 8) = *(const short8*)tmp;
            }
        }
        __syncthreads();   // T reusable for next half
    }

    // col denominators: reduce d2acc across rt within wave, then LDS
#pragma unroll
    for (int m = 8; m < 64; m <<= 1)
#pragma unroll
        for (int t = 0; t < 8; t++) d2acc[t] += __shfl_xor(d2acc[t], m);
    const int lane = tid & 63, wave = tid >> 6;
    if (lane < 8)
#pragma unroll
        for (int t = 0; t < 8; t++) dw2[wave][lane * 8 + t] = d2acc[t];
    __syncthreads();
    if (tid < 64)
        atomicAdd(&d2[b * NCn + c0 + tid],
                  dw2[0][tid] + dw2[1][tid] + dw2[2][tid] + dw2[3][tid]);
}

// ---------------------------------------------------------------------------
// Sum 4 split-K fp32 partials, scale row (b*NC+c) by 1/d2 -> bf16
// ---------------------------------------------------------------------------
__global__ __launch_bounds__(256) void reduce_scale_bf16(
    const float* __restrict__ Pp, const float* __restrict__ d2,
    bf16* __restrict__ out, long n4, long stride)
{
    long i = (long)blockIdx.x * 256 + threadIdx.x;
    if (i < n4) {
        float4 a = ((const float4*)Pp)[i];
#pragma unroll
        for (int s = 1; s < 4; s++) {
            float4 v = ((const float4*)(Pp + (long)s * stride))[i];
            a.x += v.x; a.y += v.y; a.z += v.z; a.w += v.w;
        }
        float inv = 1.0f / d2[i / (Dn / 4)];
        out[i * 4 + 0] = __float2bfloat16(a.x * inv);
        out[i * 4 + 1] = __float2bfloat16(a.y * inv);
        out[i * 4 + 2] = __float2bfloat16(a.z * inv);
        out[i * 4 + 3] = __float2bfloat16(a.w * inv);
    }
}

// ---------------------------------------------------------------------------
// fp32 [R x C] -> bf16 row-major copy AND bf16 [C x R] transpose, batched z.
// Round-9 v2 (verified): float4 loads, short8 stores both outputs.
// ---------------------------------------------------------------------------
__global__ __launch_bounds__(256) void cvt_both(
    const float* __restrict__ in, bf16* __restrict__ out_rm,
    bf16* __restrict__ out_t, int R, int C)
{
    __shared__ float tile[32][33];
    const long boff = (long)blockIdx.z * (long)R * C;
    in += boff; out_rm += boff; out_t += boff;
    const int c0 = blockIdx.x * 32, r0 = blockIdx.y * 32;
    const int tid = threadIdx.x;

    {
        const int rr = tid >> 3, cc = (tid & 7) * 4;
        float4 v = *(const float4*)(in + (long)(r0 + rr) * C + c0 + cc);
        tile[rr][cc + 0] = v.x;
        tile[rr][cc + 1] = v.y;
        tile[rr][cc + 2] = v.z;
        tile[rr][cc + 3] = v.w;
    }
    __syncthreads();

    if (tid < 128) {
        const int rr = tid >> 2, ch = (tid & 3) * 8;
        bf16 tmp[8] __attribute__((aligned(16)));
#pragma unroll
        for (int w = 0; w < 8; w++)
            tmp[w] = __float2bfloat16(tile[rr][ch + w]);
        *(short8*)(out_rm + (long)(r0 + rr) * C + c0 + ch) = *(const short8*)tmp;
    } else {
        const int t2 = tid - 128;
        const int cc2 = t2 >> 2, ch = (t2 & 3) * 8;
        bf16 tmp[8] __attribute__((aligned(16)));
#pragma unroll
        for (int w = 0; w < 8; w++)
            tmp[w] = __float2bfloat16(tile[ch + w][cc2]);
        *(short8*)(out_t + (long)(c0 + cc2) * R + r0 + ch) = *(const short8*)tmp;
    }
}

// ---------------------------------------------------------------------------
extern "C" void kernel_launch(void* const* d_in, const int* in_sizes, int n_in,
                              void* d_out, int out_size, void* d_ws, size_t ws_size,
                              hipStream_t stream)
{
    const float* Xp = (const float*)d_in[0];  // [4,4096,512]
    const float* Xc = (const float*)d_in[1];  // [4,1024,512]
    float* out = (float*)d_out;               // [4,4096,1024]

    constexpr int B = Bn, NP = NPn, NC = NCn, D = Dn;
    constexpr float SCALE = 0.044194173824159216f;  // 1/sqrt(512)

    // workspace layout (bytes), ~164 MB
    char* ws = (char*)d_ws;
    bf16*   Qp     = (bf16*)(ws);                   // 16.78 MB [B,NP,D]
    bf16*   Kc     = (bf16*)(ws + 16777216);        //  4.19 MB [B,NC,D]
    bf16*   KcT    = (bf16*)(ws + 20971520);        //  4.19 MB [B,D,NC]
    bf16*   XpT    = (bf16*)(ws + 25165824);        // 16.78 MB [B,D,NP]
    bf16*   S      = (bf16*)(ws + 41943040);        // 33.55 MB [B,NP,NC]; later Hp overlays
    bf16*   A1u    = (bf16*)(ws + 75497472);        // 33.55 MB [B,NP,NC]
    bf16*   A2u    = (bf16*)(ws + 109051904);       // 33.55 MB [B,NC,NP]; rp/cp overlay pre-softmax
    bf16*   H1u    = (bf16*)(ws + 142606336);       // 16.78 MB [B,NP,D]
    bf16*   H2     = (bf16*)(ws + 159383552);       //  4.19 MB [B,NC,D]
    float2* row_tm = (float2*)(ws + 163577856);     // 128 KB  [B*NP]
    float2* col_tm = (float2*)(ws + 163708928);     //  32 KB  [B*NC]
    float*  d1     = (float*)(ws + 163741696);      //  64 KB  [B*NP]
    float*  d2     = (float*)(ws + 163807232);      //  16 KB  [B*NC]
    float4* rp     = (float4*)A2u;                  //  1.05 MB [B*4,NP]
    float4* cp     = (float4*)(ws + 109051904 + 4194304);  // 1.05 MB [B*16,NC]
    float*  Hp     = (float*)S;                     // split-K partials [4][B,NC,D] fp32 (S dead)

    // 1-2: convert + transpose inputs (one read of fp32 each)
    cvt_both<<<dim3(D / 32, NP / 32, B), dim3(256), 0, stream>>>(Xp, Qp, XpT, NP, D);
    cvt_both<<<dim3(D / 32, NC / 32, B), dim3(256), 0, stream>>>(Xc, Kc, KcT, NC, D);

    // 3: S = Qp*Kc^T*scale (bf16) -- 256x256 8-phase, fused row/col stats
    gemm256<bf16, false, true><<<dim3(NC / 256, NP / 256, B), dim3(512), 0, stream>>>(
        Qp, Kc, S, NP, NC, D, (long)NP * D, (long)NC * D, (long)NP * NC,
        SCALE, B, nullptr, rp, cp);
    // 4: finalize thr/max (rows: 4 partials, cols: 16); zero denoms
    stats_final<<<dim3((B * NP + B * NC) / 256), dim3(256), 0, stream>>>(
        rp, cp, row_tm, col_tm, d1, d2);
    // 5: merged softmax -> A1u + A2u (transposed), denoms via atomics
    softmax_merged<<<dim3(NC / 64, NP / 256, B), dim3(256), 0, stream>>>(
        S, row_tm, col_tm, d1, d2, A1u, A2u);
    // 6+7 FUSED: H1u = A1u*KcT^T (bf16)  ||  Hp = A2u*XpT^T (fp32, split-4)
    //   1024 blocks x 256 thr, 64 KB LDS -> 2 blocks/CU co-residency.
    gemm128_fused<<<dim3(1024), dim3(256), 0, stream>>>(
        A1u, KcT, H1u, A2u, XpT, Hp);
    // 8: H2 = sum(Hp) / d2 -> bf16
    {
        long n = (long)B * NC * D;
        reduce_scale_bf16<<<dim3((n / 4 + 255) / 256), dim3(256), 0, stream>>>(
            Hp, d2, H2, n / 4, n);
    }
    // 9: out = diag(1/d1) * H1u * H2^T   [B,NP,NC] fp32 -- 256x256 8-phase
    gemm256<float, true, false><<<dim3(NC / 256, NP / 256, B), dim3(512), 0, stream>>>(
        H1u, H2, out, NP, NC, D, (long)NP * D, (long)NC * D, (long)NP * NC,
        1.0f, B, d1, nullptr, nullptr);
}